// Round 1
// baseline (813.557 us; speedup 1.0000x reference)
//
#include <hip/hip_runtime.h>
#include <hip/hip_bf16.h>
#include <stdint.h>

#define B_DIM 4
#define NKK 4096
#define NQQ 4096
#define DD 64
#define HH 256

__device__ __forceinline__ float fexp2(float x) { return __builtin_amdgcn_exp2f(x); }
__device__ __forceinline__ unsigned fbits(float x) { return __float_as_uint(x); }
__device__ __forceinline__ float bflo(unsigned u) { return __uint_as_float(u << 16); }
__device__ __forceinline__ float bfhi(unsigned u) { return __uint_as_float(u & 0xffff0000u); }
__device__ __forceinline__ unsigned packbf(float a, float b) {
  // truncating f32->bf16 pair pack (element0 in low half)
  return (fbits(a) >> 16) | (fbits(b) & 0xffff0000u);
}

// ---------------------------------------------------------------------------
// MLP kernel: out[n,o] = (h2 @ W3^T + b3)[n,o]  (optionally * X[n,o])
//   h1 = relu(X @ W1^T + b1)   [n,256]
//   h2 = relu(h1 @ W2^T + b2)  [n,256]
// 32 tokens per workgroup; all-f32 (precision required: score path amplifies
// MLP error by ~score (~10x) in the logits).
// ---------------------------------------------------------------------------
__global__ __launch_bounds__(256, 2) void mlp_kernel(
    const float* __restrict__ X,
    const float* __restrict__ W1, const float* __restrict__ B1,
    const float* __restrict__ W2, const float* __restrict__ B2,
    const float* __restrict__ W3, const float* __restrict__ B3,
    float* __restrict__ outp, int mulx)
{
  __shared__ float h1s[32][HH];   // 32 KB
  __shared__ float h2s[32][HH];   // 32 KB
  const int tid = threadIdx.x;
  const int t0 = blockIdx.x * 32;
  const float4* X4 = (const float4*)X;

  // ---- layer 1: each thread owns one of 256 channels, all 32 tokens ----
  {
    const int ch = tid;
    const float bias = B1[ch];
    float acc[32];
#pragma unroll
    for (int t = 0; t < 32; ++t) acc[t] = bias;
    const float4* Wr = (const float4*)(W1 + ch * 64);
    for (int kc = 0; kc < 16; ++kc) {
      float4 w = Wr[kc];
#pragma unroll
      for (int t = 0; t < 32; ++t) {
        float4 x = X4[(t0 + t) * 16 + kc];   // uniform address -> scalar load
        acc[t] += w.x * x.x + w.y * x.y + w.z * x.z + w.w * x.w;
      }
    }
#pragma unroll
    for (int t = 0; t < 32; ++t) h1s[t][ch] = fmaxf(acc[t], 0.0f);
  }
  __syncthreads();

  // ---- layer 2: thread -> channels (g, g+128), token half th ----
  {
    const int g = tid & 127;
    const int th = tid >> 7;          // wave-uniform
    const float bia = B2[g], bib = B2[g + 128];
    float a0[16], a1[16];
#pragma unroll
    for (int t = 0; t < 16; ++t) { a0[t] = bia; a1[t] = bib; }
    const float4* WA = (const float4*)(W2 + g * 256);
    const float4* WB = (const float4*)(W2 + (g + 128) * 256);
    for (int kc = 0; kc < 64; ++kc) {
      float4 wa = WA[kc];
      float4 wb = WB[kc];
#pragma unroll
      for (int t = 0; t < 16; ++t) {
        float4 h = *(const float4*)&h1s[th * 16 + t][kc * 4];  // LDS broadcast
        a0[t] += wa.x * h.x + wa.y * h.y + wa.z * h.z + wa.w * h.w;
        a1[t] += wb.x * h.x + wb.y * h.y + wb.z * h.z + wb.w * h.w;
      }
    }
#pragma unroll
    for (int t = 0; t < 16; ++t) {
      h2s[th * 16 + t][g]       = fmaxf(a0[t], 0.0f);
      h2s[th * 16 + t][g + 128] = fmaxf(a1[t], 0.0f);
    }
  }
  __syncthreads();

  // ---- layer 3: thread -> out channel o (64), token group tg (8 tokens) ----
  {
    const int o = tid & 63;
    const int tg = tid >> 6;          // wave-uniform
    const float bias = B3[o];
    float acc[8];
#pragma unroll
    for (int t = 0; t < 8; ++t) acc[t] = bias;
    const float4* Wr = (const float4*)(W3 + o * 256);
    for (int kc = 0; kc < 64; ++kc) {
      float4 w = Wr[kc];
#pragma unroll
      for (int t = 0; t < 8; ++t) {
        float4 h = *(const float4*)&h2s[tg * 8 + t][kc * 4];   // LDS broadcast
        acc[t] += w.x * h.x + w.y * h.y + w.z * h.z + w.w * h.w;
      }
    }
#pragma unroll
    for (int t = 0; t < 8; ++t) {
      const int row = t0 + tg * 8 + t;
      float v = acc[t];
      if (mulx) v *= X[row * 64 + o];
      outp[row * 64 + o] = v;        // coalesced (o consecutive within wave)
    }
  }
}

// ---------------------------------------------------------------------------
// Flash attention over L1-distance scores.
//   score[i,j] = sum_d |Ks[i,d]-Qs[j,d]| ; attn = softmax_i(-0.5*score^2)
//   out[q,:]   = (sum_i attn * V[i,:]) * Wo[q,:]
// Workgroup: 32 queries, 4 waves each scanning NKK/4 keys (32-key tiles) with
// independent online softmax; merged at the end via LDS.
// Per-lane score tile: 4q x 4k (lq=lane>>3 selects q-block, lk=lane&7 k-block).
// LDS tiles XOR-swizzled so the 8-unique-row b128 reads are conflict-free.
// ---------------------------------------------------------------------------
__global__ __launch_bounds__(256, 2) void attn_kernel(
    const float* __restrict__ Ksg, const float* __restrict__ Qsg,
    const float* __restrict__ Vg,  const float* __restrict__ Wog,
    float* __restrict__ outp)
{
  __shared__ float qsw[32 * 64];                // 8 KB  (swizzled f32)
  __shared__ float ksw[4][32 * 64];             // 32 KB (swizzled f32; reused as O-merge buffer)
  __shared__ unsigned short vsw[4][32 * 72];    // 18 KB (bf16, row stride 72)
  __shared__ unsigned short psw[4][32 * 36];    // 9 KB  (bf16 P tile, row stride 36)
  __shared__ float mbuf[4][32];
  __shared__ float lbuf[4][32];

  const int tid  = threadIdx.x;
  const int w    = tid >> 6;
  const int lane = tid & 63;
  const int lq   = lane >> 3;
  const int lk   = lane & 7;
  const int b    = blockIdx.y;
  const int qt   = blockIdx.x * 32;

  // stage Q_scale tile (shared by all waves), swizzled
  {
    const int row = tid >> 3;
    const int c0  = (tid & 7) * 2;
    const float4* Q4 = (const float4*)Qsg;
    float4 g0 = Q4[(b * NQQ + qt + row) * 16 + c0];
    float4 g1 = Q4[(b * NQQ + qt + row) * 16 + c0 + 1];
    const int key = (row >> 2) & 7;
    *(float4*)&qsw[row * 64 + ((c0 ^ key) << 2)]       = g0;
    *(float4*)&qsw[row * 64 + (((c0 + 1) ^ key) << 2)] = g1;
  }
  __syncthreads();

  float m_i[4], l_i[4], O[4][8];
#pragma unroll
  for (int i = 0; i < 4; ++i) {
    m_i[i] = -3.0e38f;
    l_i[i] = 0.0f;
#pragma unroll
    for (int d = 0; d < 8; ++d) O[i][d] = 0.0f;
  }

  const int kstart = w * (NKK / 4);
  const float4* K4 = (const float4*)Ksg;
  const float4* V4 = (const float4*)Vg;
  const float NEG_HALF_LOG2E = -0.72134752044448170f;  // -0.5*log2(e)

  // prefetch tile 0 into registers
  float4 kpre[8], vpre[8];
#pragma unroll
  for (int c = 0; c < 8; ++c) {
    const int row = c * 4 + (lane >> 4);
    const int ci  = lane & 15;
    kpre[c] = K4[(b * NKK + kstart + row) * 16 + ci];
    vpre[c] = V4[(b * NKK + kstart + row) * 16 + ci];
  }

  for (int it = 0; it < (NKK / 4) / 32; ++it) {
    // ---- stage prefetched regs -> LDS (wave-private; no barrier needed) ----
#pragma unroll
    for (int c = 0; c < 8; ++c) {
      const int row = c * 4 + (lane >> 4);     // row>>2 == c  -> swizzle key c
      const int ci  = lane & 15;
      *(float4*)&ksw[w][row * 64 + ((ci ^ c) << 2)] = kpre[c];
      unsigned d0 = packbf(vpre[c].x, vpre[c].y);
      unsigned d1 = packbf(vpre[c].z, vpre[c].w);
      *(uint2*)&vsw[w][row * 72 + ci * 4] = make_uint2(d0, d1);
    }
    // ---- prefetch next tile (overlaps with compute below) ----
    {
      const int itn = (it + 1 < (NKK / 4) / 32) ? it + 1 : it;
      const int kb  = kstart + itn * 32;
#pragma unroll
      for (int c = 0; c < 8; ++c) {
        const int row = c * 4 + (lane >> 4);
        const int ci  = lane & 15;
        kpre[c] = K4[(b * NKK + kb + row) * 16 + ci];
        vpre[c] = V4[(b * NKK + kb + row) * 16 + ci];
      }
    }

    // ---- score: s[i][j] = sum_d |Ks - Qs|, f32, 2 VALU/term ----
    float s[4][4];
#pragma unroll
    for (int i = 0; i < 4; ++i)
#pragma unroll
      for (int j = 0; j < 4; ++j) s[i][j] = 0.0f;

#pragma unroll 4
    for (int dc = 0; dc < 16; ++dc) {
      float4 qv[4], kv[4];
#pragma unroll
      for (int i = 0; i < 4; ++i)
        qv[i] = *(const float4*)&qsw[(4 * lq + i) * 64 + ((dc ^ lq) << 2)];
#pragma unroll
      for (int j = 0; j < 4; ++j)
        kv[j] = *(const float4*)&ksw[w][(4 * lk + j) * 64 + ((dc ^ lk) << 2)];
#pragma unroll
      for (int i = 0; i < 4; ++i)
#pragma unroll
        for (int j = 0; j < 4; ++j) {
          s[i][j] += fabsf(qv[i].x - kv[j].x);
          s[i][j] += fabsf(qv[i].y - kv[j].y);
          s[i][j] += fabsf(qv[i].z - kv[j].z);
          s[i][j] += fabsf(qv[i].w - kv[j].w);
        }
    }

    // ---- online softmax (base-2 domain), per q-row across the 8-lane k-group ----
    float p[4][4];
#pragma unroll
    for (int i = 0; i < 4; ++i) {
      float rm = -3.0e38f;
#pragma unroll
      for (int j = 0; j < 4; ++j) {
        float t = s[i][j] * s[i][j] * NEG_HALF_LOG2E;
        p[i][j] = t;
        rm = fmaxf(rm, t);
      }
      rm = fmaxf(rm, __shfl_xor(rm, 1));
      rm = fmaxf(rm, __shfl_xor(rm, 2));
      rm = fmaxf(rm, __shfl_xor(rm, 4));
      const float mn = fmaxf(m_i[i], rm);
      const float alpha = fexp2(m_i[i] - mn);
      m_i[i] = mn;
      float rs = 0.0f;
#pragma unroll
      for (int j = 0; j < 4; ++j) {
        float e = fexp2(p[i][j] - mn);
        p[i][j] = e;
        rs += e;
      }
      rs += __shfl_xor(rs, 1);
      rs += __shfl_xor(rs, 2);
      rs += __shfl_xor(rs, 4);
      l_i[i] = l_i[i] * alpha + rs;
#pragma unroll
      for (int d = 0; d < 8; ++d) O[i][d] *= alpha;
    }

    // ---- write P (bf16) to LDS for the k-redistribution ----
#pragma unroll
    for (int i = 0; i < 4; ++i) {
      unsigned d0 = packbf(p[i][0], p[i][1]);
      unsigned d1 = packbf(p[i][2], p[i][3]);
      *(uint2*)&psw[w][(4 * lq + i) * 36 + 4 * lk] = make_uint2(d0, d1);
    }

    // ---- P·V accumulate: lane owns q rows 4lq+i, d-slice lk*8..lk*8+7 ----
#pragma unroll 2
    for (int kc = 0; kc < 8; ++kc) {
      uint2 pr[4];
#pragma unroll
      for (int i = 0; i < 4; ++i)
        pr[i] = *(const uint2*)&psw[w][(4 * lq + i) * 36 + kc * 4];
      uint4 vr[4];
#pragma unroll
      for (int kk = 0; kk < 4; ++kk)
        vr[kk] = *(const uint4*)&vsw[w][(kc * 4 + kk) * 72 + lk * 8];
#pragma unroll
      for (int kk = 0; kk < 4; ++kk) {
        const float v0 = bflo(vr[kk].x), v1 = bfhi(vr[kk].x);
        const float v2 = bflo(vr[kk].y), v3 = bfhi(vr[kk].y);
        const float v4 = bflo(vr[kk].z), v5 = bfhi(vr[kk].z);
        const float v6 = bflo(vr[kk].w), v7 = bfhi(vr[kk].w);
#pragma unroll
        for (int i = 0; i < 4; ++i) {
          const unsigned pu = (kk < 2) ? pr[i].x : pr[i].y;
          const float pv = (kk & 1) ? bfhi(pu) : bflo(pu);
          O[i][0] += pv * v0;
          O[i][1] += pv * v1;
          O[i][2] += pv * v2;
          O[i][3] += pv * v3;
          O[i][4] += pv * v4;
          O[i][5] += pv * v5;
          O[i][6] += pv * v6;
          O[i][7] += pv * v7;
        }
      }
    }
  }

  // ---- cross-wave merge of (m, l, O) ----
  if (lk == 0) {
#pragma unroll
    for (int i = 0; i < 4; ++i) {
      mbuf[w][4 * lq + i] = m_i[i];
      lbuf[w][4 * lq + i] = l_i[i];
    }
  }
#pragma unroll
  for (int i = 0; i < 4; ++i) {
    float4 o0 = make_float4(O[i][0], O[i][1], O[i][2], O[i][3]);
    float4 o1 = make_float4(O[i][4], O[i][5], O[i][6], O[i][7]);
    *(float4*)&ksw[w][(4 * lq + i) * 64 + lk * 8]     = o0;   // reuse ksw as O buffer
    *(float4*)&ksw[w][(4 * lq + i) * 64 + lk * 8 + 4] = o1;
  }
  __syncthreads();
  {
    const int q = tid >> 3;
    const int dbase = (tid & 7) * 8;
    const float m0 = mbuf[0][q], m1 = mbuf[1][q], m2 = mbuf[2][q], m3 = mbuf[3][q];
    const float M = fmaxf(fmaxf(m0, m1), fmaxf(m2, m3));
    const float s0 = fexp2(m0 - M), s1 = fexp2(m1 - M);
    const float s2 = fexp2(m2 - M), s3 = fexp2(m3 - M);
    const float L = lbuf[0][q] * s0 + lbuf[1][q] * s1 + lbuf[2][q] * s2 + lbuf[3][q] * s3;
    const float rL = 1.0f / L;   // L >= 1 always (wave holding global max has l >= 1)
    const int gbase = (b * NQQ + qt + q) * 64 + dbase;
#pragma unroll
    for (int c = 0; c < 8; ++c) {
      const int d = dbase + c;
      float o = s0 * ksw[0][q * 64 + d] + s1 * ksw[1][q * 64 + d] +
                s2 * ksw[2][q * 64 + d] + s3 * ksw[3][q * 64 + d];
      outp[gbase + c] = o * rL * Wog[gbase + c];
    }
  }
}

// ---------------------------------------------------------------------------
extern "C" void kernel_launch(void* const* d_in, const int* in_sizes, int n_in,
                              void* d_out, int out_size, void* d_ws, size_t ws_size,
                              hipStream_t stream) {
  (void)in_sizes; (void)n_in; (void)out_size; (void)ws_size;
  const float* KEY   = (const float*)d_in[0];
  const float* VALUE = (const float*)d_in[1];
  const float* QUERY = (const float*)d_in[2];
  const float* W1w = (const float*)d_in[3];
  const float* W1b = (const float*)d_in[4];
  const float* W2w = (const float*)d_in[5];
  const float* W2b = (const float*)d_in[6];
  const float* W3w = (const float*)d_in[7];
  const float* W3b = (const float*)d_in[8];
  const float* Wo1w = (const float*)d_in[9];
  const float* Wo1b = (const float*)d_in[10];
  const float* Wo2w = (const float*)d_in[11];
  const float* Wo2b = (const float*)d_in[12];
  const float* Wo3w = (const float*)d_in[13];
  const float* Wo3b = (const float*)d_in[14];

  float* ws = (float*)d_ws;
  const size_t tsz = (size_t)B_DIM * NKK * DD;  // 1M floats = 4 MB
  float* Ks = ws;
  float* Qs = ws + tsz;
  float* Wo = ws + 2 * tsz;
  float* outf = (float*)d_out;

  // Wk-scale of KEY, Wq-scale of QUERY (shared weights), Wo of QUERY
  mlp_kernel<<<dim3((B_DIM * NKK) / 32), 256, 0, stream>>>(
      KEY, W1w, W1b, W2w, W2b, W3w, W3b, Ks, 1);
  mlp_kernel<<<dim3((B_DIM * NQQ) / 32), 256, 0, stream>>>(
      QUERY, W1w, W1b, W2w, W2b, W3w, W3b, Qs, 1);
  mlp_kernel<<<dim3((B_DIM * NQQ) / 32), 256, 0, stream>>>(
      QUERY, Wo1w, Wo1b, Wo2w, Wo2b, Wo3w, Wo3b, Wo, 0);

  attn_kernel<<<dim3(NQQ / 32, B_DIM), 256, 0, stream>>>(Ks, Qs, VALUE, Wo, outf);
}

// Round 2
// 683.066 us; speedup vs baseline: 1.1910x; 1.1910x over previous
//
#include <hip/hip_runtime.h>
#include <hip/hip_bf16.h>
#include <stdint.h>

#define B_DIM 4
#define NKK 4096
#define NQQ 4096
#define DD 64
#define HH 256

typedef __attribute__((ext_vector_type(4))) float floatx4;
typedef __attribute__((ext_vector_type(8))) short bf16x8;

__device__ __forceinline__ float fexp2(float x) { return __builtin_amdgcn_exp2f(x); }
__device__ __forceinline__ unsigned fbits(float x) { return __float_as_uint(x); }
__device__ __forceinline__ unsigned packbf(float a, float b) {
  // truncating f32->bf16 pair pack (element0 in low half)
  return (fbits(a) >> 16) | (fbits(b) & 0xffff0000u);
}

// ---------------------------------------------------------------------------
// V pre-transpose: Vt[b][d][k] = bf16(V[b][k][d]).  Lets the attention kernel
// read MFMA B-fragments (8 contiguous k per lane) as single ds_read_b128s.
// ---------------------------------------------------------------------------
__global__ __launch_bounds__(256) void vtrans_kernel(
    const float* __restrict__ V, unsigned short* __restrict__ Vt)
{
  __shared__ unsigned short t[64][80];  // [d][k], padded
  const int tid = threadIdx.x;
  const int b = blockIdx.y;
  const int k0 = blockIdx.x * 64;
  const float4* V4 = (const float4*)V;

  {
    const int r = tid & 63;        // k row
    const int c4 = tid >> 6;       // which 16-d group
#pragma unroll
    for (int j = 0; j < 4; ++j) {
      float4 f = V4[((size_t)(b * NKK + k0 + r)) * 16 + c4 * 4 + j];
      const int d0 = c4 * 16 + j * 4;
      t[d0 + 0][r] = (unsigned short)(fbits(f.x) >> 16);
      t[d0 + 1][r] = (unsigned short)(fbits(f.y) >> 16);
      t[d0 + 2][r] = (unsigned short)(fbits(f.z) >> 16);
      t[d0 + 3][r] = (unsigned short)(fbits(f.w) >> 16);
    }
  }
  __syncthreads();
  {
    const int d = tid >> 2;
    const int kc = tid & 3;
    uint4 u0 = *(const uint4*)&t[d][kc * 16];
    uint4 u1 = *(const uint4*)&t[d][kc * 16 + 8];
    unsigned short* dst = Vt + ((size_t)(b * 64 + d)) * NKK + k0 + kc * 16;
    *(uint4*)dst = u0;
    *(uint4*)(dst + 8) = u1;
  }
}

// ---------------------------------------------------------------------------
// MLP body (all f32 — score path amplifies MLP error by ~score(~10x), bf16
// weights would blow the 0.022 absmax budget). 32 tokens per block.
// ---------------------------------------------------------------------------
__device__ __forceinline__ void mlp_body(
    int t0, const float* __restrict__ X,
    const float* __restrict__ W1, const float* __restrict__ B1,
    const float* __restrict__ W2, const float* __restrict__ B2,
    const float* __restrict__ W3, const float* __restrict__ B3,
    float* __restrict__ outp, int mulx,
    float (*xs)[64], float (*h1s)[HH], float (*h2s)[HH], int tid)
{
  const float4* X4 = (const float4*)X;

  // stage X tile (coalesced) -> LDS; later reads are wave-uniform broadcasts
  {
    const int row = tid >> 3;
    const int c0 = (tid & 7) * 2;
    float4 g0 = X4[(size_t)(t0 + row) * 16 + c0];
    float4 g1 = X4[(size_t)(t0 + row) * 16 + c0 + 1];
    *(float4*)&xs[row][c0 * 4] = g0;
    *(float4*)&xs[row][c0 * 4 + 4] = g1;
  }
  __syncthreads();

  // ---- layer 1: thread = channel, all 32 tokens ----
  {
    const int ch = tid;
    const float bias = B1[ch];
    float acc[32];
#pragma unroll
    for (int t = 0; t < 32; ++t) acc[t] = bias;
    const float4* Wr = (const float4*)(W1 + ch * 64);
    for (int kc = 0; kc < 16; ++kc) {
      float4 w = Wr[kc];
#pragma unroll
      for (int t = 0; t < 32; ++t) {
        float4 x = *(const float4*)&xs[t][kc * 4];   // broadcast
        acc[t] += w.x * x.x + w.y * x.y + w.z * x.z + w.w * x.w;
      }
    }
#pragma unroll
    for (int t = 0; t < 32; ++t) h1s[t][ch] = fmaxf(acc[t], 0.0f);
  }
  __syncthreads();

  // ---- layer 2: thread -> channels (g, g+128), token half th ----
  {
    const int g = tid & 127;
    const int th = tid >> 7;
    const float bia = B2[g], bib = B2[g + 128];
    float a0[16], a1[16];
#pragma unroll
    for (int t = 0; t < 16; ++t) { a0[t] = bia; a1[t] = bib; }
    const float4* WA = (const float4*)(W2 + g * 256);
    const float4* WB = (const float4*)(W2 + (g + 128) * 256);
    for (int kc = 0; kc < 64; ++kc) {
      float4 wa = WA[kc];
      float4 wb = WB[kc];
#pragma unroll
      for (int t = 0; t < 16; ++t) {
        float4 h = *(const float4*)&h1s[th * 16 + t][kc * 4];
        a0[t] += wa.x * h.x + wa.y * h.y + wa.z * h.z + wa.w * h.w;
        a1[t] += wb.x * h.x + wb.y * h.y + wb.z * h.z + wb.w * h.w;
      }
    }
#pragma unroll
    for (int t = 0; t < 16; ++t) {
      h2s[th * 16 + t][g]       = fmaxf(a0[t], 0.0f);
      h2s[th * 16 + t][g + 128] = fmaxf(a1[t], 0.0f);
    }
  }
  __syncthreads();

  // ---- layer 3: thread -> out channel o (64), token group tg (8) ----
  {
    const int o = tid & 63;
    const int tg = tid >> 6;
    const float bias = B3[o];
    float acc[8];
#pragma unroll
    for (int t = 0; t < 8; ++t) acc[t] = bias;
    const float4* Wr = (const float4*)(W3 + o * 256);
    for (int kc = 0; kc < 64; ++kc) {
      float4 w = Wr[kc];
#pragma unroll
      for (int t = 0; t < 8; ++t) {
        float4 h = *(const float4*)&h2s[tg * 8 + t][kc * 4];
        acc[t] += w.x * h.x + w.y * h.y + w.z * h.z + w.w * h.w;
      }
    }
#pragma unroll
    for (int t = 0; t < 8; ++t) {
      const int lrow = tg * 8 + t;
      float v = acc[t];
      if (mulx) v *= xs[lrow][o];
      outp[(size_t)(t0 + lrow) * 64 + o] = v;
    }
  }
}

__global__ __launch_bounds__(256, 2) void mlp3_kernel(
    const float* __restrict__ KEY, const float* __restrict__ QUERY,
    const float* __restrict__ W1w, const float* __restrict__ W1b,
    const float* __restrict__ W2w, const float* __restrict__ W2b,
    const float* __restrict__ W3w, const float* __restrict__ W3b,
    const float* __restrict__ Wo1w, const float* __restrict__ Wo1b,
    const float* __restrict__ Wo2w, const float* __restrict__ Wo2b,
    const float* __restrict__ Wo3w, const float* __restrict__ Wo3b,
    float* __restrict__ Ks, float* __restrict__ Qs, float* __restrict__ Wo)
{
  __shared__ float xs[32][64];     // 8 KB
  __shared__ float h1s[32][HH];    // 32 KB
  __shared__ float h2s[32][HH];    // 32 KB
  const int g = blockIdx.x;
  const int tid = threadIdx.x;
  if (g < 512) {
    mlp_body(g * 32, KEY, W1w, W1b, W2w, W2b, W3w, W3b, Ks, 1, xs, h1s, h2s, tid);
  } else if (g < 1024) {
    mlp_body((g - 512) * 32, QUERY, W1w, W1b, W2w, W2b, W3w, W3b, Qs, 1, xs, h1s, h2s, tid);
  } else {
    mlp_body((g - 1024) * 32, QUERY, Wo1w, Wo1b, Wo2w, Wo2b, Wo3w, Wo3b, Wo, 0, xs, h1s, h2s, tid);
  }
}

// ---------------------------------------------------------------------------
// Flash attention over L1-distance scores, P·V on MFMA.
//   score[i,j] = sum_d |Ks[i,d]-Qs[j,d]| ; attn = softmax_i(-0.5*score^2)
//   out[q,:]   = (sum_i attn * V[i,:]) * Wo[q,:]
// 32 queries/wg; 4 waves with private k-ranges (1024 keys, 32-key tiles) —
// zero barriers in the main loop. Per-lane score tile 4q x 4k.
// P goes through LDS (bf16) into MFMA A-layout; V comes pre-transposed
// (Vt[d][k] bf16) so B-frags are single ds_read_b128s. O accumulates in
// MFMA C-layout; alpha rescale is broadcast via a tiny LDS buffer.
// l is kept as per-lane partials (alpha is row-uniform) and reduced once
// in the epilogue — no per-tile sum shuffles.
// ---------------------------------------------------------------------------
__global__ __launch_bounds__(256, 2) void attn_kernel(
    const float* __restrict__ Ksg, const float* __restrict__ Qsg,
    const unsigned short* __restrict__ Vtg, const float* __restrict__ Wog,
    float* __restrict__ outp)
{
  __shared__ float qsA[32 * 64];              // 8 KB, unswizzled
  __shared__ float ksA[4][32 * 64];           // 32 KB, xor-swizzled; reused as O-merge buf
  __shared__ unsigned short vtB[4][64 * 40];  // 20 KB, Vt tile [d][k] bf16, stride 40
  __shared__ unsigned short psB[4][32 * 40];  // 10 KB, P tile [q][k] bf16, stride 40
  __shared__ float abA[4][32];                // alpha per q-row
  __shared__ float mbufA[4][32];
  __shared__ float lbufA[4][32];

  const int tid  = threadIdx.x;
  const int w    = tid >> 6;
  const int lane = tid & 63;
  const int lq   = lane >> 3;
  const int lk   = lane & 7;
  const int l15  = lane & 15;
  const int quad = lane >> 4;
  const int lk16 = lk << 4;
  const int b    = blockIdx.y;
  const int qt   = blockIdx.x * 32;

  // stage Q tile (shared by all waves), unswizzled: q-reads have <=2 unique
  // addrs per quarter-wave -> at worst free 2-way conflicts, and immediate
  // read offsets (zero per-iter address math).
  {
    const int row = tid >> 3;
    const int c0  = (tid & 7) * 2;
    const float4* Q4 = (const float4*)Qsg;
    float4 g0 = Q4[(size_t)(b * NQQ + qt + row) * 16 + c0];
    float4 g1 = Q4[(size_t)(b * NQQ + qt + row) * 16 + c0 + 1];
    *(float4*)&qsA[row * 64 + c0 * 4]     = g0;
    *(float4*)&qsA[row * 64 + c0 * 4 + 4] = g1;
  }
  __syncthreads();

  float m_i[4], l_i[4];
  floatx4 acc[2][4];   // O in MFMA C-layout: [m-block][n-block]
#pragma unroll
  for (int i = 0; i < 4; ++i) { m_i[i] = -3.0e38f; l_i[i] = 0.0f; }
#pragma unroll
  for (int mb = 0; mb < 2; ++mb)
#pragma unroll
    for (int nb = 0; nb < 4; ++nb)
#pragma unroll
      for (int r = 0; r < 4; ++r) acc[mb][nb][r] = 0.0f;

  const int kstart = w * (NKK / 4);
  const float4* K4 = (const float4*)Ksg;
  const unsigned short* vg = Vtg + ((size_t)b * 64 + lane) * NKK + kstart;
  const float NEG_HALF_LOG2E = -0.72134752044448170f;  // -0.5*log2(e)

  const int krow = (lane >> 4);        // staging row-in-group
  const int kci  = lane & 15;          // staging chunk

  // prefetch tile 0
  float4 kpre[8];
  uint4 vtpre[4];
#pragma unroll
  for (int c = 0; c < 8; ++c)
    kpre[c] = K4[(size_t)(b * NKK + kstart + c * 4 + krow) * 16 + kci];
#pragma unroll
  for (int c = 0; c < 4; ++c)
    vtpre[c] = *(const uint4*)(vg + c * 8);

  const float4* qb = (const float4*)&qsA[(4 * lq) * 64];
  const char* kb = (const char*)&ksA[w][(4 * lk) * 64];

  for (int it = 0; it < (NKK / 4) / 32; ++it) {
    // ---- store prefetched tile -> LDS (wave-private, no barrier) ----
#pragma unroll
    for (int c = 0; c < 8; ++c) {
      const int row = c * 4 + krow;             // row>>2 == c -> swizzle key c
      *(float4*)&ksA[w][row * 64 + ((kci ^ c) << 2)] = kpre[c];
    }
#pragma unroll
    for (int c = 0; c < 4; ++c)
      *(uint4*)&vtB[w][lane * 40 + c * 8] = vtpre[c];

    // ---- prefetch next tile ----
    {
      const int itn = (it + 1 < 32) ? it + 1 : it;
#pragma unroll
      for (int c = 0; c < 8; ++c)
        kpre[c] = K4[(size_t)(b * NKK + kstart + itn * 32 + c * 4 + krow) * 16 + kci];
#pragma unroll
      for (int c = 0; c < 4; ++c)
        vtpre[c] = *(const uint4*)(vg + itn * 32 + c * 8);
    }

    // ---- score: s[i][j] = sum_d |Ks-Qs| (f32). Q via imm offsets; K via
    // 2 VALU/dc (xor+add) thanks to the store-side swizzle. ----
    float s[4][4];
#pragma unroll
    for (int i = 0; i < 4; ++i)
#pragma unroll
      for (int j = 0; j < 4; ++j) s[i][j] = 0.0f;

#pragma unroll
    for (int dc = 0; dc < 16; ++dc) {
      const int koff = (dc * 16) ^ lk16;
      float4 qv[4], kv[4];
#pragma unroll
      for (int i = 0; i < 4; ++i) qv[i] = qb[i * 16 + dc];
#pragma unroll
      for (int j = 0; j < 4; ++j) kv[j] = *(const float4*)(kb + j * 256 + koff);
#pragma unroll
      for (int i = 0; i < 4; ++i)
#pragma unroll
        for (int j = 0; j < 4; ++j) {
          s[i][j] += fabsf(qv[i].x - kv[j].x);
          s[i][j] += fabsf(qv[i].y - kv[j].y);
          s[i][j] += fabsf(qv[i].z - kv[j].z);
          s[i][j] += fabsf(qv[i].w - kv[j].w);
        }
    }

    // ---- online softmax (base-2 domain). Row max via min(s). Only the max
    // needs cross-lane reduce; l stays per-lane (alpha is row-uniform). ----
    float a_row[4];
#pragma unroll
    for (int i = 0; i < 4; ++i) {
      float smin = fminf(fminf(s[i][0], s[i][1]), fminf(s[i][2], s[i][3]));
      smin = fminf(smin, __shfl_xor(smin, 1));
      smin = fminf(smin, __shfl_xor(smin, 2));
      smin = fminf(smin, __shfl_xor(smin, 4));
      const float tmax = smin * smin * NEG_HALF_LOG2E;
      const float mn = fmaxf(m_i[i], tmax);
      a_row[i] = fexp2(m_i[i] - mn);
      m_i[i] = mn;
      float pv[4];
      float ps = 0.0f;
#pragma unroll
      for (int j = 0; j < 4; ++j) {
        const float sv = s[i][j];
        const float e = fexp2(fmaf(sv * NEG_HALF_LOG2E, sv, -mn));
        pv[j] = e;
        ps += e;
      }
      l_i[i] = fmaf(l_i[i], a_row[i], ps);
      *(uint2*)&psB[w][(4 * lq + i) * 40 + 4 * lk] =
          make_uint2(packbf(pv[0], pv[1]), packbf(pv[2], pv[3]));
    }
    if (lk == 0)
      *(float4*)&abA[w][4 * lq] = make_float4(a_row[0], a_row[1], a_row[2], a_row[3]);

    // ---- P·V on MFMA: O[32q][64d] += P[32q][32k] · V[32k][64d] ----
    {
      bf16x8 afrag[2], bfrag[4];
#pragma unroll
      for (int mb = 0; mb < 2; ++mb)
        afrag[mb] = *(const bf16x8*)&psB[w][(mb * 16 + l15) * 40 + quad * 8];
#pragma unroll
      for (int nb = 0; nb < 4; ++nb)
        bfrag[nb] = *(const bf16x8*)&vtB[w][(nb * 16 + l15) * 40 + quad * 8];

      float ar0[4], ar1[4];
      *(float4*)ar0 = *(const float4*)&abA[w][quad * 4];        // rows quad*4+r
      *(float4*)ar1 = *(const float4*)&abA[w][16 + quad * 4];   // rows 16+quad*4+r

#pragma unroll
      for (int nb = 0; nb < 4; ++nb) {
#pragma unroll
        for (int r = 0; r < 4; ++r) {
          acc[0][nb][r] *= ar0[r];
          acc[1][nb][r] *= ar1[r];
        }
        acc[0][nb] = __builtin_amdgcn_mfma_f32_16x16x32_bf16(afrag[0], bfrag[nb], acc[0][nb], 0, 0, 0);
        acc[1][nb] = __builtin_amdgcn_mfma_f32_16x16x32_bf16(afrag[1], bfrag[nb], acc[1][nb], 0, 0, 0);
      }
    }
  }

  // ---- epilogue: reduce l across lk lanes; publish m,l,O; merge waves ----
#pragma unroll
  for (int i = 0; i < 4; ++i) {
    float l = l_i[i];
    l += __shfl_xor(l, 1);
    l += __shfl_xor(l, 2);
    l += __shfl_xor(l, 4);
    l_i[i] = l;
  }
  if (lk == 0) {
    *(float4*)&mbufA[w][4 * lq] = make_float4(m_i[0], m_i[1], m_i[2], m_i[3]);
    *(float4*)&lbufA[w][4 * lq] = make_float4(l_i[0], l_i[1], l_i[2], l_i[3]);
  }
  // O (C-layout) -> LDS merge buffer (reuse ksA[w]), row-major [q][d]
#pragma unroll
  for (int mb = 0; mb < 2; ++mb)
#pragma unroll
    for (int nb = 0; nb < 4; ++nb)
#pragma unroll
      for (int r = 0; r < 4; ++r)
        ksA[w][(mb * 16 + quad * 4 + r) * 64 + nb * 16 + l15] = acc[mb][nb][r];
  __syncthreads();

  {
    const int q = tid >> 3;
    const int dbase = (tid & 7) * 8;
    const float m0 = mbufA[0][q], m1 = mbufA[1][q], m2 = mbufA[2][q], m3 = mbufA[3][q];
    const float M = fmaxf(fmaxf(m0, m1), fmaxf(m2, m3));
    const float s0 = fexp2(m0 - M), s1 = fexp2(m1 - M);
    const float s2 = fexp2(m2 - M), s3 = fexp2(m3 - M);
    const float L = lbufA[0][q] * s0 + lbufA[1][q] * s1 + lbufA[2][q] * s2 + lbufA[3][q] * s3;
    const float rL = 1.0f / L;   // L >= ~1 (wave holding global max has l >= 1)
    const size_t gbase = (size_t)(b * NQQ + qt + q) * 64 + dbase;
#pragma unroll
    for (int c = 0; c < 8; ++c) {
      const int d = dbase + c;
      float o = s0 * ksA[0][q * 64 + d] + s1 * ksA[1][q * 64 + d] +
                s2 * ksA[2][q * 64 + d] + s3 * ksA[3][q * 64 + d];
      outp[gbase + c] = o * rL * Wog[gbase + c];
    }
  }
}

// ---------------------------------------------------------------------------
extern "C" void kernel_launch(void* const* d_in, const int* in_sizes, int n_in,
                              void* d_out, int out_size, void* d_ws, size_t ws_size,
                              hipStream_t stream) {
  (void)in_sizes; (void)n_in; (void)out_size; (void)ws_size;
  const float* KEY   = (const float*)d_in[0];
  const float* VALUE = (const float*)d_in[1];
  const float* QUERY = (const float*)d_in[2];
  const float* W1w = (const float*)d_in[3];
  const float* W1b = (const float*)d_in[4];
  const float* W2w = (const float*)d_in[5];
  const float* W2b = (const float*)d_in[6];
  const float* W3w = (const float*)d_in[7];
  const float* W3b = (const float*)d_in[8];
  const float* Wo1w = (const float*)d_in[9];
  const float* Wo1b = (const float*)d_in[10];
  const float* Wo2w = (const float*)d_in[11];
  const float* Wo2b = (const float*)d_in[12];
  const float* Wo3w = (const float*)d_in[13];
  const float* Wo3b = (const float*)d_in[14];

  float* ws = (float*)d_ws;
  const size_t tsz = (size_t)B_DIM * NKK * DD;  // 1M floats = 4 MB
  float* Ks = ws;
  float* Qs = ws + tsz;
  float* Wo = ws + 2 * tsz;
  unsigned short* Vtg = (unsigned short*)(ws + 3 * tsz);  // 2 MB bf16
  float* outf = (float*)d_out;

  vtrans_kernel<<<dim3(NKK / 64, B_DIM), 256, 0, stream>>>(VALUE, Vtg);
  mlp3_kernel<<<dim3(1536), 256, 0, stream>>>(
      KEY, QUERY, W1w, W1b, W2w, W2b, W3w, W3b,
      Wo1w, Wo1b, Wo2w, Wo2b, Wo3w, Wo3b, Ks, Qs, Wo);
  attn_kernel<<<dim3(NQQ / 32, B_DIM), 256, 0, stream>>>(Ks, Qs, Vtg, Wo, outf);
}

// Round 3
// 663.002 us; speedup vs baseline: 1.2271x; 1.0303x over previous
//
#include <hip/hip_runtime.h>
#include <hip/hip_bf16.h>
#include <stdint.h>

#define B_DIM 4
#define NKK 4096
#define NQQ 4096
#define DD 64
#define HH 256

typedef __attribute__((ext_vector_type(4))) float floatx4;
typedef __attribute__((ext_vector_type(8))) short bf16x8;

__device__ __forceinline__ float fexp2(float x) { return __builtin_amdgcn_exp2f(x); }
__device__ __forceinline__ unsigned fbits(float x) { return __float_as_uint(x); }
__device__ __forceinline__ unsigned packbf(float a, float b) {
  // truncating f32->bf16 pair pack (element0 in low half)
  return (fbits(a) >> 16) | (fbits(b) & 0xffff0000u);
}

// f32 LDS tile row stride: 68 floats = 272B = 17 banks*16B. The odd factor 17
// spreads row-starts across banks: rows r -> bank 17r mod 32, so the 8 rows
// read simultaneously by the lq/lk groups hit 8 distinct bank-quads
// (conflict-free), vs stride 64 where ALL rows alias to bank 0 (the round-2
// 8-way conflict, SQ_LDS_BANK_CONFLICT=33.9M).
#define FSTRIDE 68
#define FSTRIDE4 17

// ---------------------------------------------------------------------------
// V pre-transpose: Vt[b][d][k] = bf16(V[b][k][d]).
// ---------------------------------------------------------------------------
__global__ __launch_bounds__(256) void vtrans_kernel(
    const float* __restrict__ V, unsigned short* __restrict__ Vt)
{
  __shared__ unsigned short t[64][80];  // [d][k], padded
  const int tid = threadIdx.x;
  const int b = blockIdx.y;
  const int k0 = blockIdx.x * 64;
  const float4* V4 = (const float4*)V;

  {
    const int r = tid & 63;        // k row
    const int c4 = tid >> 6;       // which 16-d group
#pragma unroll
    for (int j = 0; j < 4; ++j) {
      float4 f = V4[((size_t)(b * NKK + k0 + r)) * 16 + c4 * 4 + j];
      const int d0 = c4 * 16 + j * 4;
      t[d0 + 0][r] = (unsigned short)(fbits(f.x) >> 16);
      t[d0 + 1][r] = (unsigned short)(fbits(f.y) >> 16);
      t[d0 + 2][r] = (unsigned short)(fbits(f.z) >> 16);
      t[d0 + 3][r] = (unsigned short)(fbits(f.w) >> 16);
    }
  }
  __syncthreads();
  {
    const int d = tid >> 2;
    const int kc = tid & 3;
    uint4 u0 = *(const uint4*)&t[d][kc * 16];
    uint4 u1 = *(const uint4*)&t[d][kc * 16 + 8];
    unsigned short* dst = Vt + ((size_t)(b * 64 + d)) * NKK + k0 + kc * 16;
    *(uint4*)dst = u0;
    *(uint4*)(dst + 8) = u1;
  }
}

// ---------------------------------------------------------------------------
// MLP body (all f32 — score path amplifies MLP error ~10x; bf16 weights blow
// the 0.022 absmax budget). 32 tokens per block. kc loops unrolled x4 to
// batch the L2 weight loads (round-2: dependent ~200cyc L2 hits per iter).
// ---------------------------------------------------------------------------
__device__ __forceinline__ void mlp_body(
    int t0, const float* __restrict__ X,
    const float* __restrict__ W1, const float* __restrict__ B1,
    const float* __restrict__ W2, const float* __restrict__ B2,
    const float* __restrict__ W3, const float* __restrict__ B3,
    float* __restrict__ outp, int mulx,
    float (*xs)[64], float (*h1s)[HH], float (*h2s)[HH], int tid)
{
  const float4* X4 = (const float4*)X;

  // stage X tile (coalesced) -> LDS; later reads are wave-uniform broadcasts
  {
    const int row = tid >> 3;
    const int c0 = (tid & 7) * 2;
    float4 g0 = X4[(size_t)(t0 + row) * 16 + c0];
    float4 g1 = X4[(size_t)(t0 + row) * 16 + c0 + 1];
    *(float4*)&xs[row][c0 * 4] = g0;
    *(float4*)&xs[row][c0 * 4 + 4] = g1;
  }
  __syncthreads();

  // ---- layer 1: thread = channel, all 32 tokens ----
  {
    const int ch = tid;
    const float bias = B1[ch];
    float acc[32];
#pragma unroll
    for (int t = 0; t < 32; ++t) acc[t] = bias;
    const float4* Wr = (const float4*)(W1 + ch * 64);
#pragma unroll 4
    for (int kc = 0; kc < 16; ++kc) {
      float4 w = Wr[kc];
#pragma unroll
      for (int t = 0; t < 32; ++t) {
        float4 x = *(const float4*)&xs[t][kc * 4];   // broadcast
        acc[t] += w.x * x.x + w.y * x.y + w.z * x.z + w.w * x.w;
      }
    }
#pragma unroll
    for (int t = 0; t < 32; ++t) h1s[t][ch] = fmaxf(acc[t], 0.0f);
  }
  __syncthreads();

  // ---- layer 2: thread -> channels (g, g+128), token half th ----
  {
    const int g = tid & 127;
    const int th = tid >> 7;
    const float bia = B2[g], bib = B2[g + 128];
    float a0[16], a1[16];
#pragma unroll
    for (int t = 0; t < 16; ++t) { a0[t] = bia; a1[t] = bib; }
    const float4* WA = (const float4*)(W2 + g * 256);
    const float4* WB = (const float4*)(W2 + (g + 128) * 256);
#pragma unroll 4
    for (int kc = 0; kc < 64; ++kc) {
      float4 wa = WA[kc];
      float4 wb = WB[kc];
#pragma unroll
      for (int t = 0; t < 16; ++t) {
        float4 h = *(const float4*)&h1s[th * 16 + t][kc * 4];
        a0[t] += wa.x * h.x + wa.y * h.y + wa.z * h.z + wa.w * h.w;
        a1[t] += wb.x * h.x + wb.y * h.y + wb.z * h.z + wb.w * h.w;
      }
    }
#pragma unroll
    for (int t = 0; t < 16; ++t) {
      h2s[th * 16 + t][g]       = fmaxf(a0[t], 0.0f);
      h2s[th * 16 + t][g + 128] = fmaxf(a1[t], 0.0f);
    }
  }
  __syncthreads();

  // ---- layer 3: thread -> out channel o (64), token group tg (8) ----
  {
    const int o = tid & 63;
    const int tg = tid >> 6;
    const float bias = B3[o];
    float acc[8];
#pragma unroll
    for (int t = 0; t < 8; ++t) acc[t] = bias;
    const float4* Wr = (const float4*)(W3 + o * 256);
#pragma unroll 4
    for (int kc = 0; kc < 64; ++kc) {
      float4 w = Wr[kc];
#pragma unroll
      for (int t = 0; t < 8; ++t) {
        float4 h = *(const float4*)&h2s[tg * 8 + t][kc * 4];
        acc[t] += w.x * h.x + w.y * h.y + w.z * h.z + w.w * h.w;
      }
    }
#pragma unroll
    for (int t = 0; t < 8; ++t) {
      const int lrow = tg * 8 + t;
      float v = acc[t];
      if (mulx) v *= xs[lrow][o];
      outp[(size_t)(t0 + lrow) * 64 + o] = v;
    }
  }
}

__global__ __launch_bounds__(256, 2) void mlp3_kernel(
    const float* __restrict__ KEY, const float* __restrict__ QUERY,
    const float* __restrict__ W1w, const float* __restrict__ W1b,
    const float* __restrict__ W2w, const float* __restrict__ W2b,
    const float* __restrict__ W3w, const float* __restrict__ W3b,
    const float* __restrict__ Wo1w, const float* __restrict__ Wo1b,
    const float* __restrict__ Wo2w, const float* __restrict__ Wo2b,
    const float* __restrict__ Wo3w, const float* __restrict__ Wo3b,
    float* __restrict__ Ks, float* __restrict__ Qs, float* __restrict__ Wo)
{
  __shared__ float xs[32][64];     // 8 KB
  __shared__ float h1s[32][HH];    // 32 KB
  __shared__ float h2s[32][HH];    // 32 KB
  const int g = blockIdx.x;
  const int tid = threadIdx.x;
  if (g < 512) {
    mlp_body(g * 32, KEY, W1w, W1b, W2w, W2b, W3w, W3b, Ks, 1, xs, h1s, h2s, tid);
  } else if (g < 1024) {
    mlp_body((g - 512) * 32, QUERY, W1w, W1b, W2w, W2b, W3w, W3b, Qs, 1, xs, h1s, h2s, tid);
  } else {
    mlp_body((g - 1024) * 32, QUERY, Wo1w, Wo1b, Wo2w, Wo2b, Wo3w, Wo3b, Wo, 0, xs, h1s, h2s, tid);
  }
}

// ---------------------------------------------------------------------------
// Flash attention over L1-distance scores, P·V on MFMA.
// 32 queries/wg; 4 waves with private k-ranges (1024 keys, 32-key tiles) —
// zero barriers in the main loop. Per-lane score tile 4q x 4k.
// All f32 LDS tiles use stride-68 rows (conflict-free, immediate offsets, no
// swizzle); vtB writes column-staggered by (lane>>3)&3 (reader compensates).
// ---------------------------------------------------------------------------
__global__ __launch_bounds__(256, 2) void attn_kernel(
    const float* __restrict__ Ksg, const float* __restrict__ Qsg,
    const unsigned short* __restrict__ Vtg, const float* __restrict__ Wog,
    float* __restrict__ outp)
{
  __shared__ float qsA[32 * FSTRIDE];           // 8.7 KB
  __shared__ float ksA[4][32 * FSTRIDE];        // 34.8 KB; reused as O-merge buf
  __shared__ unsigned short vtB[4][64 * 40];    // 20 KB, Vt tile [d][k] bf16
  __shared__ unsigned short psB[4][32 * 40];    // 10 KB, P tile [q][k] bf16
  __shared__ float abA[4][32];                  // alpha per q-row
  __shared__ float mbufA[4][32];
  __shared__ float lbufA[4][32];

  const int tid  = threadIdx.x;
  const int w    = tid >> 6;
  const int lane = tid & 63;
  const int lq   = lane >> 3;
  const int lk   = lane & 7;
  const int l15  = lane & 15;
  const int quad = lane >> 4;
  const int b    = blockIdx.y;
  const int qt   = blockIdx.x * 32;

  // stage Q tile (shared by all waves)
  {
    const int row = tid >> 3;
    const int c0  = (tid & 7) * 2;
    const float4* Q4 = (const float4*)Qsg;
    float4 g0 = Q4[(size_t)(b * NQQ + qt + row) * 16 + c0];
    float4 g1 = Q4[(size_t)(b * NQQ + qt + row) * 16 + c0 + 1];
    *(float4*)&qsA[row * FSTRIDE + c0 * 4]     = g0;
    *(float4*)&qsA[row * FSTRIDE + c0 * 4 + 4] = g1;
  }
  __syncthreads();

  float m_i[4], l_i[4];
  floatx4 acc[2][4];   // O in MFMA C-layout: [m-block][n-block]
#pragma unroll
  for (int i = 0; i < 4; ++i) { m_i[i] = -3.0e38f; l_i[i] = 0.0f; }
#pragma unroll
  for (int mb = 0; mb < 2; ++mb)
#pragma unroll
    for (int nb = 0; nb < 4; ++nb)
#pragma unroll
      for (int r = 0; r < 4; ++r) acc[mb][nb][r] = 0.0f;

  const int kstart = w * (NKK / 4);
  const float4* K4 = (const float4*)Ksg;
  const unsigned short* vg = Vtg + ((size_t)b * 64 + lane) * NKK + kstart;
  const float NEG_HALF_LOG2E = -0.72134752044448170f;  // -0.5*log2(e)

  const int krow = (lane >> 4);        // staging row-in-group
  const int kci  = lane & 15;          // staging chunk
  const int vst  = (lane >> 3) & 3;    // vtB write-column stagger key

  // prefetch tile 0
  float4 kpre[8];
  uint4 vtpre[4];
#pragma unroll
  for (int c = 0; c < 8; ++c)
    kpre[c] = K4[(size_t)(b * NKK + kstart + c * 4 + krow) * 16 + kci];
#pragma unroll
  for (int c = 0; c < 4; ++c)
    vtpre[c] = *(const uint4*)(vg + c * 8);

  const float4* qb = (const float4*)&qsA[(4 * lq) * FSTRIDE];
  const float4* kb = (const float4*)&ksA[w][(4 * lk) * FSTRIDE];

  // vtB read-column keys for the B-frag loads (compensate write stagger)
  int vcol[4];
#pragma unroll
  for (int nb = 0; nb < 4; ++nb)
    vcol[nb] = (((quad + (l15 >> 3) + 2 * nb) & 3) << 3);

  for (int it = 0; it < (NKK / 4) / 32; ++it) {
    // ---- store prefetched tile -> LDS (wave-private, no barrier) ----
#pragma unroll
    for (int c = 0; c < 8; ++c)
      *(float4*)&ksA[w][(c * 4 + krow) * FSTRIDE + kci * 4] = kpre[c];
#pragma unroll
    for (int c = 0; c < 4; ++c)
      *(uint4*)&vtB[w][lane * 40 + (((c + vst) & 3) << 3)] = vtpre[(0 + c) & 3 ? (c) : (c)]; // plain c; stagger is in the address
#pragma unroll
    for (int c = 0; c < 4; ++c)
      ;  // (loop above already stored all 4 chunks)

    // ---- prefetch next tile ----
    {
      const int itn = (it + 1 < 32) ? it + 1 : it;
#pragma unroll
      for (int c = 0; c < 8; ++c)
        kpre[c] = K4[(size_t)(b * NKK + kstart + itn * 32 + c * 4 + krow) * 16 + kci];
#pragma unroll
      for (int c = 0; c < 4; ++c)
        vtpre[c] = *(const uint4*)(vg + itn * 32 + c * 8);
    }

    // ---- score: s[i][j] = sum_d |Ks-Qs| (f32), all-immediate LDS offsets ----
    float s[4][4];
#pragma unroll
    for (int i = 0; i < 4; ++i)
#pragma unroll
      for (int j = 0; j < 4; ++j) s[i][j] = 0.0f;

#pragma unroll
    for (int dc = 0; dc < 16; ++dc) {
      float4 qv[4], kv[4];
#pragma unroll
      for (int i = 0; i < 4; ++i) qv[i] = qb[i * FSTRIDE4 + dc];
#pragma unroll
      for (int j = 0; j < 4; ++j) kv[j] = kb[j * FSTRIDE4 + dc];
#pragma unroll
      for (int i = 0; i < 4; ++i)
#pragma unroll
        for (int j = 0; j < 4; ++j) {
          s[i][j] += fabsf(qv[i].x - kv[j].x);
          s[i][j] += fabsf(qv[i].y - kv[j].y);
          s[i][j] += fabsf(qv[i].z - kv[j].z);
          s[i][j] += fabsf(qv[i].w - kv[j].w);
        }
    }

    // ---- online softmax (base-2 domain); row max via min(s); l per-lane ----
    float a_row[4];
#pragma unroll
    for (int i = 0; i < 4; ++i) {
      float smin = fminf(fminf(s[i][0], s[i][1]), fminf(s[i][2], s[i][3]));
      smin = fminf(smin, __shfl_xor(smin, 1));
      smin = fminf(smin, __shfl_xor(smin, 2));
      smin = fminf(smin, __shfl_xor(smin, 4));
      const float tmax = smin * smin * NEG_HALF_LOG2E;
      const float mn = fmaxf(m_i[i], tmax);
      a_row[i] = fexp2(m_i[i] - mn);
      m_i[i] = mn;
      float pv[4];
      float ps = 0.0f;
#pragma unroll
      for (int j = 0; j < 4; ++j) {
        const float sv = s[i][j];
        const float e = fexp2(fmaf(sv * NEG_HALF_LOG2E, sv, -mn));
        pv[j] = e;
        ps += e;
      }
      l_i[i] = fmaf(l_i[i], a_row[i], ps);
      *(uint2*)&psB[w][(4 * lq + i) * 40 + 4 * lk] =
          make_uint2(packbf(pv[0], pv[1]), packbf(pv[2], pv[3]));
    }
    if (lk == 0)
      *(float4*)&abA[w][4 * lq] = make_float4(a_row[0], a_row[1], a_row[2], a_row[3]);

    // ---- P·V on MFMA: O[32q][64d] += P[32q][32k] · V[32k][64d] ----
    {
      bf16x8 afrag[2], bfrag[4];
#pragma unroll
      for (int mb = 0; mb < 2; ++mb)
        afrag[mb] = *(const bf16x8*)&psB[w][(mb * 16 + l15) * 40 + quad * 8];
#pragma unroll
      for (int nb = 0; nb < 4; ++nb)
        bfrag[nb] = *(const bf16x8*)&vtB[w][(nb * 16 + l15) * 40 + vcol[nb]];

      float ar0[4], ar1[4];
      *(float4*)ar0 = *(const float4*)&abA[w][quad * 4];        // rows quad*4+r
      *(float4*)ar1 = *(const float4*)&abA[w][16 + quad * 4];   // rows 16+quad*4+r

#pragma unroll
      for (int nb = 0; nb < 4; ++nb) {
#pragma unroll
        for (int r = 0; r < 4; ++r) {
          acc[0][nb][r] *= ar0[r];
          acc[1][nb][r] *= ar1[r];
        }
        acc[0][nb] = __builtin_amdgcn_mfma_f32_16x16x32_bf16(afrag[0], bfrag[nb], acc[0][nb], 0, 0, 0);
        acc[1][nb] = __builtin_amdgcn_mfma_f32_16x16x32_bf16(afrag[1], bfrag[nb], acc[1][nb], 0, 0, 0);
      }
    }
  }

  // ---- epilogue: reduce l across lk lanes; publish m,l,O; merge waves ----
#pragma unroll
  for (int i = 0; i < 4; ++i) {
    float l = l_i[i];
    l += __shfl_xor(l, 1);
    l += __shfl_xor(l, 2);
    l += __shfl_xor(l, 4);
    l_i[i] = l;
  }
  if (lk == 0) {
    *(float4*)&mbufA[w][4 * lq] = make_float4(m_i[0], m_i[1], m_i[2], m_i[3]);
    *(float4*)&lbufA[w][4 * lq] = make_float4(l_i[0], l_i[1], l_i[2], l_i[3]);
  }
  // O (C-layout) -> LDS merge buffer (reuse ksA[w]), row-major [q][d] stride 64
#pragma unroll
  for (int mb = 0; mb < 2; ++mb)
#pragma unroll
    for (int nb = 0; nb < 4; ++nb)
#pragma unroll
      for (int r = 0; r < 4; ++r)
        ksA[w][(mb * 16 + quad * 4 + r) * 64 + nb * 16 + l15] = acc[mb][nb][r];
  __syncthreads();

  {
    const int q = tid >> 3;
    const int dbase = (tid & 7) * 8;
    const float m0 = mbufA[0][q], m1 = mbufA[1][q], m2 = mbufA[2][q], m3 = mbufA[3][q];
    const float M = fmaxf(fmaxf(m0, m1), fmaxf(m2, m3));
    const float s0 = fexp2(m0 - M), s1 = fexp2(m1 - M);
    const float s2 = fexp2(m2 - M), s3 = fexp2(m3 - M);
    const float L = lbufA[0][q] * s0 + lbufA[1][q] * s1 + lbufA[2][q] * s2 + lbufA[3][q] * s3;
    const float rL = 1.0f / L;   // L >= ~1 (wave holding global max has l >= 1)
    const size_t gbase = (size_t)(b * NQQ + qt + q) * 64 + dbase;
#pragma unroll
    for (int c = 0; c < 8; ++c) {
      const int d = dbase + c;
      float o = s0 * ksA[0][q * 64 + d] + s1 * ksA[1][q * 64 + d] +
                s2 * ksA[2][q * 64 + d] + s3 * ksA[3][q * 64 + d];
      outp[gbase + c] = o * rL * Wog[gbase + c];
    }
  }
}

// ---------------------------------------------------------------------------
extern "C" void kernel_launch(void* const* d_in, const int* in_sizes, int n_in,
                              void* d_out, int out_size, void* d_ws, size_t ws_size,
                              hipStream_t stream) {
  (void)in_sizes; (void)n_in; (void)out_size; (void)ws_size;
  const float* KEY   = (const float*)d_in[0];
  const float* VALUE = (const float*)d_in[1];
  const float* QUERY = (const float*)d_in[2];
  const float* W1w = (const float*)d_in[3];
  const float* W1b = (const float*)d_in[4];
  const float* W2w = (const float*)d_in[5];
  const float* W2b = (const float*)d_in[6];
  const float* W3w = (const float*)d_in[7];
  const float* W3b = (const float*)d_in[8];
  const float* Wo1w = (const float*)d_in[9];
  const float* Wo1b = (const float*)d_in[10];
  const float* Wo2w = (const float*)d_in[11];
  const float* Wo2b = (const float*)d_in[12];
  const float* Wo3w = (const float*)d_in[13];
  const float* Wo3b = (const float*)d_in[14];

  float* ws = (float*)d_ws;
  const size_t tsz = (size_t)B_DIM * NKK * DD;  // 1M floats = 4 MB
  float* Ks = ws;
  float* Qs = ws + tsz;
  float* Wo = ws + 2 * tsz;
  unsigned short* Vtg = (unsigned short*)(ws + 3 * tsz);  // 2 MB bf16
  float* outf = (float*)d_out;

  vtrans_kernel<<<dim3(NKK / 64, B_DIM), 256, 0, stream>>>(VALUE, Vtg);
  mlp3_kernel<<<dim3(1536), 256, 0, stream>>>(
      KEY, QUERY, W1w, W1b, W2w, W2b, W3w, W3b,
      Wo1w, Wo1b, Wo2w, Wo2b, Wo3w, Wo3b, Ks, Qs, Wo);
  attn_kernel<<<dim3(NQQ / 32, B_DIM), 256, 0, stream>>>(Ks, Qs, Vtg, Wo, outf);
}

// Round 4
// 599.478 us; speedup vs baseline: 1.3571x; 1.1060x over previous
//
#include <hip/hip_runtime.h>
#include <hip/hip_bf16.h>
#include <stdint.h>

#define B_DIM 4
#define NKK 4096
#define NQQ 4096
#define DD 64
#define HH 256

typedef __attribute__((ext_vector_type(4))) float floatx4;
typedef __attribute__((ext_vector_type(2))) float floatx2;
typedef __attribute__((ext_vector_type(8))) short bf16x8;

__device__ __forceinline__ float fexp2(float x) { return __builtin_amdgcn_exp2f(x); }
__device__ __forceinline__ unsigned fbits(float x) { return __float_as_uint(x); }

// f32 LDS tile row stride (floats). Bank-start of row r = 4r mod 32, so a
// group of 8 CONSECUTIVE rows (lk=0..7 / lq=0..7 after the reindex below)
// spans 8 distinct bank-quads -> conflict-free b128 reads. (Round-3 bug:
// rows 4*lk+j gave bank-starts 16*lk mod 32 = {0,16} -> 4-way conflicts.)
#define FSTRIDE 68
#define FSTRIDE4 17

// ---------------------------------------------------------------------------
// V pre-transpose: Vt[b][d][k] = bf16(V[b][k][d]).
// ---------------------------------------------------------------------------
__global__ __launch_bounds__(256) void vtrans_kernel(
    const float* __restrict__ V, unsigned short* __restrict__ Vt)
{
  __shared__ unsigned short t[64][80];  // [d][k], padded
  const int tid = threadIdx.x;
  const int b = blockIdx.y;
  const int k0 = blockIdx.x * 64;
  const float4* V4 = (const float4*)V;

  {
    const int r = tid & 63;        // k row
    const int c4 = tid >> 6;       // which 16-d group
#pragma unroll
    for (int j = 0; j < 4; ++j) {
      float4 f = V4[((size_t)(b * NKK + k0 + r)) * 16 + c4 * 4 + j];
      const int d0 = c4 * 16 + j * 4;
      t[d0 + 0][r] = (unsigned short)(fbits(f.x) >> 16);
      t[d0 + 1][r] = (unsigned short)(fbits(f.y) >> 16);
      t[d0 + 2][r] = (unsigned short)(fbits(f.z) >> 16);
      t[d0 + 3][r] = (unsigned short)(fbits(f.w) >> 16);
    }
  }
  __syncthreads();
  {
    const int d = tid >> 2;
    const int kc = tid & 3;
    uint4 u0 = *(const uint4*)&t[d][kc * 16];
    uint4 u1 = *(const uint4*)&t[d][kc * 16 + 8];
    unsigned short* dst = Vt + ((size_t)(b * 64 + d)) * NKK + k0 + kc * 16;
    *(uint4*)dst = u0;
    *(uint4*)(dst + 8) = u1;
  }
}

// ---------------------------------------------------------------------------
// MLP body (all f32 — score path amplifies MLP error ~10x; bf16 weights blow
// the 0.022 absmax budget). 32 tokens per block.
// ---------------------------------------------------------------------------
__device__ __forceinline__ void mlp_body(
    int t0, const float* __restrict__ X,
    const float* __restrict__ W1, const float* __restrict__ B1,
    const float* __restrict__ W2, const float* __restrict__ B2,
    const float* __restrict__ W3, const float* __restrict__ B3,
    float* __restrict__ outp, int mulx,
    float (*xs)[64], float (*h1s)[HH], float (*h2s)[HH], int tid)
{
  const float4* X4 = (const float4*)X;

  {
    const int row = tid >> 3;
    const int c0 = (tid & 7) * 2;
    float4 g0 = X4[(size_t)(t0 + row) * 16 + c0];
    float4 g1 = X4[(size_t)(t0 + row) * 16 + c0 + 1];
    *(float4*)&xs[row][c0 * 4] = g0;
    *(float4*)&xs[row][c0 * 4 + 4] = g1;
  }
  __syncthreads();

  // ---- layer 1 ----
  {
    const int ch = tid;
    const float bias = B1[ch];
    float acc[32];
#pragma unroll
    for (int t = 0; t < 32; ++t) acc[t] = bias;
    const float4* Wr = (const float4*)(W1 + ch * 64);
#pragma unroll 4
    for (int kc = 0; kc < 16; ++kc) {
      float4 w = Wr[kc];
#pragma unroll
      for (int t = 0; t < 32; ++t) {
        float4 x = *(const float4*)&xs[t][kc * 4];
        acc[t] += w.x * x.x + w.y * x.y + w.z * x.z + w.w * x.w;
      }
    }
#pragma unroll
    for (int t = 0; t < 32; ++t) h1s[t][ch] = fmaxf(acc[t], 0.0f);
  }
  __syncthreads();

  // ---- layer 2 ----
  {
    const int g = tid & 127;
    const int th = tid >> 7;
    const float bia = B2[g], bib = B2[g + 128];
    float a0[16], a1[16];
#pragma unroll
    for (int t = 0; t < 16; ++t) { a0[t] = bia; a1[t] = bib; }
    const float4* WA = (const float4*)(W2 + g * 256);
    const float4* WB = (const float4*)(W2 + (g + 128) * 256);
#pragma unroll 4
    for (int kc = 0; kc < 64; ++kc) {
      float4 wa = WA[kc];
      float4 wb = WB[kc];
#pragma unroll
      for (int t = 0; t < 16; ++t) {
        float4 h = *(const float4*)&h1s[th * 16 + t][kc * 4];
        a0[t] += wa.x * h.x + wa.y * h.y + wa.z * h.z + wa.w * h.w;
        a1[t] += wb.x * h.x + wb.y * h.y + wb.z * h.z + wb.w * h.w;
      }
    }
#pragma unroll
    for (int t = 0; t < 16; ++t) {
      h2s[th * 16 + t][g]       = fmaxf(a0[t], 0.0f);
      h2s[th * 16 + t][g + 128] = fmaxf(a1[t], 0.0f);
    }
  }
  __syncthreads();

  // ---- layer 3 ----
  {
    const int o = tid & 63;
    const int tg = tid >> 6;
    const float bias = B3[o];
    float acc[8];
#pragma unroll
    for (int t = 0; t < 8; ++t) acc[t] = bias;
    const float4* Wr = (const float4*)(W3 + o * 256);
#pragma unroll 4
    for (int kc = 0; kc < 64; ++kc) {
      float4 w = Wr[kc];
#pragma unroll
      for (int t = 0; t < 8; ++t) {
        float4 h = *(const float4*)&h2s[tg * 8 + t][kc * 4];
        acc[t] += w.x * h.x + w.y * h.y + w.z * h.z + w.w * h.w;
      }
    }
#pragma unroll
    for (int t = 0; t < 8; ++t) {
      const int lrow = tg * 8 + t;
      float v = acc[t];
      if (mulx) v *= xs[lrow][o];
      outp[(size_t)(t0 + lrow) * 64 + o] = v;
    }
  }
}

__global__ __launch_bounds__(256, 2) void mlp3_kernel(
    const float* __restrict__ KEY, const float* __restrict__ QUERY,
    const float* __restrict__ W1w, const float* __restrict__ W1b,
    const float* __restrict__ W2w, const float* __restrict__ W2b,
    const float* __restrict__ W3w, const float* __restrict__ W3b,
    const float* __restrict__ Wo1w, const float* __restrict__ Wo1b,
    const float* __restrict__ Wo2w, const float* __restrict__ Wo2b,
    const float* __restrict__ Wo3w, const float* __restrict__ Wo3b,
    float* __restrict__ Ks, float* __restrict__ Qs, float* __restrict__ Wo)
{
  __shared__ float xs[32][64];
  __shared__ float h1s[32][HH];
  __shared__ float h2s[32][HH];
  const int g = blockIdx.x;
  const int tid = threadIdx.x;
  if (g < 512) {
    mlp_body(g * 32, KEY, W1w, W1b, W2w, W2b, W3w, W3b, Ks, 1, xs, h1s, h2s, tid);
  } else if (g < 1024) {
    mlp_body((g - 512) * 32, QUERY, W1w, W1b, W2w, W2b, W3w, W3b, Qs, 1, xs, h1s, h2s, tid);
  } else {
    mlp_body((g - 1024) * 32, QUERY, Wo1w, Wo1b, Wo2w, Wo2b, Wo3w, Wo3b, Wo, 0, xs, h1s, h2s, tid);
  }
}

// ---------------------------------------------------------------------------
// Flash attention over L1-distance scores, P·V on MFMA.
// Reindexed lane tiles: lane (lq,lk) owns q-rows {lq+8i} and keys {lk+8j}.
// Consecutive-row read groups -> conflict-free stride-68 b128 LDS reads.
// Score core uses float2 ops -> packed v_pk_add_f32 (1.5 VALU/dim).
// P stored at natural key columns (16 b16 scatter stores) so V layout and
// MFMA fragment reads are unchanged.
// ---------------------------------------------------------------------------
__global__ __launch_bounds__(256, 2) void attn_kernel(
    const float* __restrict__ Ksg, const float* __restrict__ Qsg,
    const unsigned short* __restrict__ Vtg, const float* __restrict__ Wog,
    float* __restrict__ outp)
{
  __shared__ float qsA[32 * FSTRIDE];           // 8.7 KB
  __shared__ float ksA[4][32 * FSTRIDE];        // 34.8 KB; reused as O-merge buf
  __shared__ unsigned short vtB[4][64 * 40];    // 20 KB, Vt tile [d][k] bf16
  __shared__ unsigned short psB[4][32 * 40];    // 10 KB, P tile [q][k] bf16
  __shared__ float abA[4][32];                  // alpha per q-row
  __shared__ float mbufA[4][32];
  __shared__ float lbufA[4][32];

  const int tid  = threadIdx.x;
  const int w    = tid >> 6;
  const int lane = tid & 63;
  const int lq   = lane >> 3;
  const int lk   = lane & 7;
  const int l15  = lane & 15;
  const int quad = lane >> 4;
  const int b    = blockIdx.y;
  const int qt   = blockIdx.x * 32;

  // stage Q tile (natural row order; only reads are reindexed)
  {
    const int row = tid >> 3;
    const int c0  = (tid & 7) * 2;
    const float4* Q4 = (const float4*)Qsg;
    float4 g0 = Q4[(size_t)(b * NQQ + qt + row) * 16 + c0];
    float4 g1 = Q4[(size_t)(b * NQQ + qt + row) * 16 + c0 + 1];
    *(float4*)&qsA[row * FSTRIDE + c0 * 4]     = g0;
    *(float4*)&qsA[row * FSTRIDE + c0 * 4 + 4] = g1;
  }
  __syncthreads();

  float m_i[4], l_i[4];
  floatx4 acc[2][4];   // O in MFMA C-layout
#pragma unroll
  for (int i = 0; i < 4; ++i) { m_i[i] = -3.0e38f; l_i[i] = 0.0f; }
#pragma unroll
  for (int mb = 0; mb < 2; ++mb)
#pragma unroll
    for (int nb = 0; nb < 4; ++nb)
#pragma unroll
      for (int r = 0; r < 4; ++r) acc[mb][nb][r] = 0.0f;

  const int kstart = w * (NKK / 4);
  const float4* K4 = (const float4*)Ksg;
  const unsigned short* vg = Vtg + ((size_t)b * 64 + lane) * NKK + kstart;
  const float NEG_HALF_LOG2E = -0.72134752044448170f;  // -0.5*log2(e)

  const int krow = (lane >> 4);        // staging row-in-group
  const int kci  = lane & 15;          // staging chunk
  const int vst  = (lane >> 3) & 3;    // vtB write-column stagger key

  // prefetch tile 0
  float4 kpre[8];
  uint4 vtpre[4];
#pragma unroll
  for (int c = 0; c < 8; ++c)
    kpre[c] = K4[(size_t)(b * NKK + kstart + c * 4 + krow) * 16 + kci];
#pragma unroll
  for (int c = 0; c < 4; ++c)
    vtpre[c] = *(const uint4*)(vg + c * 8);

  // reindexed fragment bases: lane's q-rows = lq+8i, keys = lk+8j
  const floatx4* qb = (const floatx4*)&qsA[lq * FSTRIDE];
  const floatx4* kb = (const floatx4*)&ksA[w][lk * FSTRIDE];

  // vtB read-column keys for the B-frag loads (compensate write stagger)
  int vcol[4];
#pragma unroll
  for (int nb = 0; nb < 4; ++nb)
    vcol[nb] = (((quad + (l15 >> 3) + 2 * nb) & 3) << 3);

  for (int it = 0; it < (NKK / 4) / 32; ++it) {
    // ---- store prefetched tile -> LDS (wave-private, no barrier) ----
#pragma unroll
    for (int c = 0; c < 8; ++c)
      *(float4*)&ksA[w][(c * 4 + krow) * FSTRIDE + kci * 4] = kpre[c];
#pragma unroll
    for (int c = 0; c < 4; ++c)
      *(uint4*)&vtB[w][lane * 40 + (((c + vst) & 3) << 3)] = vtpre[c];

    // ---- prefetch next tile ----
    {
      const int itn = (it + 1 < 32) ? it + 1 : it;
#pragma unroll
      for (int c = 0; c < 8; ++c)
        kpre[c] = K4[(size_t)(b * NKK + kstart + itn * 32 + c * 4 + krow) * 16 + kci];
#pragma unroll
      for (int c = 0; c < 4; ++c)
        vtpre[c] = *(const uint4*)(vg + itn * 32 + c * 8);
    }

    // ---- score: s[i][j] = sum_d |Ks[lk+8j] - Qs[lq+8i]|, packed-f32 core ----
    float s[4][4];
#pragma unroll
    for (int i = 0; i < 4; ++i)
#pragma unroll
      for (int j = 0; j < 4; ++j) s[i][j] = 0.0f;

#pragma unroll
    for (int dc = 0; dc < 16; ++dc) {
      floatx4 qv[4], kv[4];
#pragma unroll
      for (int i = 0; i < 4; ++i) qv[i] = qb[i * (8 * FSTRIDE4) + dc];
#pragma unroll
      for (int j = 0; j < 4; ++j) kv[j] = kb[j * (8 * FSTRIDE4) + dc];
#pragma unroll
      for (int i = 0; i < 4; ++i) {
        floatx2 qlo = qv[i].lo, qhi = qv[i].hi;
#pragma unroll
        for (int j = 0; j < 4; ++j) {
          floatx2 d0 = qlo - kv[j].lo;   // v_pk_add_f32 (neg)
          floatx2 d1 = qhi - kv[j].hi;
          s[i][j] += __builtin_fabsf(d0.x);
          s[i][j] += __builtin_fabsf(d0.y);
          s[i][j] += __builtin_fabsf(d1.x);
          s[i][j] += __builtin_fabsf(d1.y);
        }
      }
    }

    // ---- online softmax (base-2); row max via min(s); l per-lane ----
    float a_row[4];
#pragma unroll
    for (int i = 0; i < 4; ++i) {
      float smin = fminf(fminf(s[i][0], s[i][1]), fminf(s[i][2], s[i][3]));
      smin = fminf(smin, __shfl_xor(smin, 1));
      smin = fminf(smin, __shfl_xor(smin, 2));
      smin = fminf(smin, __shfl_xor(smin, 4));
      const float tmax = smin * smin * NEG_HALF_LOG2E;
      const float mn = fmaxf(m_i[i], tmax);
      a_row[i] = fexp2(m_i[i] - mn);
      m_i[i] = mn;
      float ps = 0.0f;
#pragma unroll
      for (int j = 0; j < 4; ++j) {
        const float sv = s[i][j];
        const float e = fexp2(fmaf(sv * NEG_HALF_LOG2E, sv, -mn));
        ps += e;
        // natural key column lk+8j (matches V layout; MFMA sums any order)
        psB[w][(lq + 8 * i) * 40 + lk + 8 * j] = (unsigned short)(fbits(e) >> 16);
      }
      l_i[i] = fmaf(l_i[i], a_row[i], ps);
    }
    if (lk == 0) {
#pragma unroll
      for (int i = 0; i < 4; ++i) abA[w][lq + 8 * i] = a_row[i];
    }

    // ---- P·V on MFMA: O[32q][64d] += P[32q][32k] · V[32k][64d] ----
    {
      bf16x8 afrag[2], bfrag[4];
#pragma unroll
      for (int mb = 0; mb < 2; ++mb)
        afrag[mb] = *(const bf16x8*)&psB[w][(mb * 16 + l15) * 40 + quad * 8];
#pragma unroll
      for (int nb = 0; nb < 4; ++nb)
        bfrag[nb] = *(const bf16x8*)&vtB[w][(nb * 16 + l15) * 40 + vcol[nb]];

      float ar0[4], ar1[4];
      *(float4*)ar0 = *(const float4*)&abA[w][quad * 4];
      *(float4*)ar1 = *(const float4*)&abA[w][16 + quad * 4];

#pragma unroll
      for (int nb = 0; nb < 4; ++nb) {
#pragma unroll
        for (int r = 0; r < 4; ++r) {
          acc[0][nb][r] *= ar0[r];
          acc[1][nb][r] *= ar1[r];
        }
        acc[0][nb] = __builtin_amdgcn_mfma_f32_16x16x32_bf16(afrag[0], bfrag[nb], acc[0][nb], 0, 0, 0);
        acc[1][nb] = __builtin_amdgcn_mfma_f32_16x16x32_bf16(afrag[1], bfrag[nb], acc[1][nb], 0, 0, 0);
      }
    }
  }

  // ---- epilogue: reduce l across lk lanes; publish m,l,O; merge waves ----
#pragma unroll
  for (int i = 0; i < 4; ++i) {
    float l = l_i[i];
    l += __shfl_xor(l, 1);
    l += __shfl_xor(l, 2);
    l += __shfl_xor(l, 4);
    l_i[i] = l;
  }
  if (lk == 0) {
#pragma unroll
    for (int i = 0; i < 4; ++i) {
      mbufA[w][lq + 8 * i] = m_i[i];
      lbufA[w][lq + 8 * i] = l_i[i];
    }
  }
  // O (C-layout, rows = natural q rows) -> merge buffer (reuse ksA[w])
#pragma unroll
  for (int mb = 0; mb < 2; ++mb)
#pragma unroll
    for (int nb = 0; nb < 4; ++nb)
#pragma unroll
      for (int r = 0; r < 4; ++r)
        ksA[w][(mb * 16 + quad * 4 + r) * 64 + nb * 16 + l15] = acc[mb][nb][r];
  __syncthreads();

  {
    const int q = tid >> 3;
    const int dbase = (tid & 7) * 8;
    const float m0 = mbufA[0][q], m1 = mbufA[1][q], m2 = mbufA[2][q], m3 = mbufA[3][q];
    const float M = fmaxf(fmaxf(m0, m1), fmaxf(m2, m3));
    const float s0 = fexp2(m0 - M), s1 = fexp2(m1 - M);
    const float s2 = fexp2(m2 - M), s3 = fexp2(m3 - M);
    const float L = lbufA[0][q] * s0 + lbufA[1][q] * s1 + lbufA[2][q] * s2 + lbufA[3][q] * s3;
    const float rL = 1.0f / L;
    const size_t gbase = (size_t)(b * NQQ + qt + q) * 64 + dbase;
#pragma unroll
    for (int c = 0; c < 8; ++c) {
      const int d = dbase + c;
      float o = s0 * ksA[0][q * 64 + d] + s1 * ksA[1][q * 64 + d] +
                s2 * ksA[2][q * 64 + d] + s3 * ksA[3][q * 64 + d];
      outp[gbase + c] = o * rL * Wog[gbase + c];
    }
  }
}

// ---------------------------------------------------------------------------
extern "C" void kernel_launch(void* const* d_in, const int* in_sizes, int n_in,
                              void* d_out, int out_size, void* d_ws, size_t ws_size,
                              hipStream_t stream) {
  (void)in_sizes; (void)n_in; (void)out_size; (void)ws_size;
  const float* KEY   = (const float*)d_in[0];
  const float* VALUE = (const float*)d_in[1];
  const float* QUERY = (const float*)d_in[2];
  const float* W1w = (const float*)d_in[3];
  const float* W1b = (const float*)d_in[4];
  const float* W2w = (const float*)d_in[5];
  const float* W2b = (const float*)d_in[6];
  const float* W3w = (const float*)d_in[7];
  const float* W3b = (const float*)d_in[8];
  const float* Wo1w = (const float*)d_in[9];
  const float* Wo1b = (const float*)d_in[10];
  const float* Wo2w = (const float*)d_in[11];
  const float* Wo2b = (const float*)d_in[12];
  const float* Wo3w = (const float*)d_in[13];
  const float* Wo3b = (const float*)d_in[14];

  float* ws = (float*)d_ws;
  const size_t tsz = (size_t)B_DIM * NKK * DD;  // 1M floats = 4 MB
  float* Ks = ws;
  float* Qs = ws + tsz;
  float* Wo = ws + 2 * tsz;
  unsigned short* Vtg = (unsigned short*)(ws + 3 * tsz);  // 2 MB bf16
  float* outf = (float*)d_out;

  vtrans_kernel<<<dim3(NKK / 64, B_DIM), 256, 0, stream>>>(VALUE, Vtg);
  mlp3_kernel<<<dim3(1536), 256, 0, stream>>>(
      KEY, QUERY, W1w, W1b, W2w, W2b, W3w, W3b,
      Wo1w, Wo1b, Wo2w, Wo2b, Wo3w, Wo3b, Ks, Qs, Wo);
  attn_kernel<<<dim3(NQQ / 32, B_DIM), 256, 0, stream>>>(Ks, Qs, Vtg, Wo, outf);
}

// Round 5
// 523.025 us; speedup vs baseline: 1.5555x; 1.1462x over previous
//
#include <hip/hip_runtime.h>
#include <hip/hip_bf16.h>
#include <stdint.h>

#define B_DIM 4
#define NKK 4096
#define NQQ 4096
#define DD 64
#define HH 256

typedef __attribute__((ext_vector_type(4))) float floatx4;
typedef __attribute__((ext_vector_type(2))) float floatx2;
typedef __attribute__((ext_vector_type(8))) short bf16x8;

__device__ __forceinline__ float fexp2(float x) { return __builtin_amdgcn_exp2f(x); }
__device__ __forceinline__ unsigned fbits(float x) { return __float_as_uint(x); }
__device__ __forceinline__ float bf2f(unsigned short u) { return __uint_as_float(((unsigned)u) << 16); }

// round-to-nearest-even split: x = h + l, h/l bf16, rel err ~2^-17
__device__ __forceinline__ void splitbf(float x, unsigned short& h, unsigned short& l) {
  unsigned u = fbits(x);
  unsigned hu = (u + 0x7fff + ((u >> 16) & 1)) & 0xffff0000u;
  h = (unsigned short)(hu >> 16);
  l = (unsigned short)(fbits(x - __uint_as_float(hu)) >> 16);
}

// f32 LDS tile row stride (floats): bank-start 4r mod 32, 8 consecutive rows
// -> 8 distinct bank-quads -> conflict-free (verified round 4: 33.9M -> 2.85M).
#define FSTRIDE 68
#define FSTRIDE4 17

// ---------------------------------------------------------------------------
// Weight split prep: per set {W1[256x64], W2[256x256], W3[64x256]} write
// h/l bf16 arrays. Set0 = (W1,W2,W3), set1 = (Wo1,Wo2,Wo3).
// Layout (shorts, per set, stride 196608): W1h@0 W1l@16384 W2h@32768
// W2l@98304 W3h@163840 W3l@180224.
// ---------------------------------------------------------------------------
__global__ __launch_bounds__(256) void wsplit_kernel(
    const float* __restrict__ W1a, const float* __restrict__ W2a, const float* __restrict__ W3a,
    const float* __restrict__ W1b, const float* __restrict__ W2b, const float* __restrict__ W3b,
    unsigned short* __restrict__ sp)
{
  int idx = blockIdx.x * 256 + threadIdx.x;       // 0..196607
  const int set = idx >= 98304;
  int r = idx - set * 98304;
  unsigned short* base = sp + (size_t)set * 196608;
  const float* src;
  unsigned short *dh, *dl;
  int j;
  if (r < 16384)      { src = set ? W1b : W1a; dh = base;          dl = base + 16384;  j = r; }
  else if (r < 81920) { src = set ? W2b : W2a; dh = base + 32768;  dl = base + 98304;  j = r - 16384; }
  else                { src = set ? W3b : W3a; dh = base + 163840; dl = base + 180224; j = r - 81920; }
  unsigned short h, l;
  splitbf(src[j], h, l);
  dh[j] = h; dl[j] = l;
}

// ---------------------------------------------------------------------------
// V pre-transpose: Vt[b][d][k] = bf16(V[b][k][d]).
// ---------------------------------------------------------------------------
__global__ __launch_bounds__(256) void vtrans_kernel(
    const float* __restrict__ V, unsigned short* __restrict__ Vt)
{
  __shared__ unsigned short t[64][80];
  const int tid = threadIdx.x;
  const int b = blockIdx.y;
  const int k0 = blockIdx.x * 64;
  const float4* V4 = (const float4*)V;
  {
    const int r = tid & 63;
    const int c4 = tid >> 6;
#pragma unroll
    for (int j = 0; j < 4; ++j) {
      float4 f = V4[((size_t)(b * NKK + k0 + r)) * 16 + c4 * 4 + j];
      const int d0 = c4 * 16 + j * 4;
      t[d0 + 0][r] = (unsigned short)(fbits(f.x) >> 16);
      t[d0 + 1][r] = (unsigned short)(fbits(f.y) >> 16);
      t[d0 + 2][r] = (unsigned short)(fbits(f.z) >> 16);
      t[d0 + 3][r] = (unsigned short)(fbits(f.w) >> 16);
    }
  }
  __syncthreads();
  {
    const int d = tid >> 2;
    const int kc = tid & 3;
    uint4 u0 = *(const uint4*)&t[d][kc * 16];
    uint4 u1 = *(const uint4*)&t[d][kc * 16 + 8];
    unsigned short* dst = Vt + ((size_t)(b * 64 + d)) * NKK + k0 + kc * 16;
    *(uint4*)dst = u0;
    *(uint4*)(dst + 8) = u1;
  }
}

// ---------------------------------------------------------------------------
// MLP on MFMA with split-bf16 precision (3 mfma per product: hh + lh + hl;
// missing ll term ~2^-18 rel -- well inside the 0.022 absmax budget that
// f32 was needed for). 32 tokens/wg, 4 waves; wave w owns output-channel
// slice [w*64, w*64+64) in L1/L2, [w*16, w*16+16) in L3.
// B-fragments (weights) read straight from L2-resident global split arrays.
// One LDS H buffer reused for h1 and h2 (barrier-separated).
// ---------------------------------------------------------------------------
#define HSTRIDE 264   // shorts; 528B = 132 dwords = 4 mod 32 -> 2-way (free)
__global__ __launch_bounds__(256, 2) void mlpmm_kernel(
    const float* __restrict__ KEY, const float* __restrict__ QUERY,
    const float* __restrict__ B1a, const float* __restrict__ B2a, const float* __restrict__ B3a,
    const float* __restrict__ B1b, const float* __restrict__ B2b, const float* __restrict__ B3b,
    const unsigned short* __restrict__ sp,
    float* __restrict__ Ks, float* __restrict__ Qs, float* __restrict__ Wo)
{
  __shared__ unsigned short Xh[32][72], Xl[32][72];        // 9.2 KB
  __shared__ unsigned short Hsh[32][HSTRIDE], Hsl[32][HSTRIDE]; // 33.8 KB
  const int tid = threadIdx.x;
  const int w = tid >> 6;
  const int lane = tid & 63;
  const int l15 = lane & 15;
  const int quad = lane >> 4;

  const int g = blockIdx.x;
  const float* X;
  float* outp;
  int mulx, t0;
  const unsigned short* wb;
  const float *b1, *b2, *b3;
  if (g < 512)       { X = KEY;   outp = Ks; mulx = 1; t0 = g * 32;          wb = sp;          b1 = B1a; b2 = B2a; b3 = B3a; }
  else if (g < 1024) { X = QUERY; outp = Qs; mulx = 1; t0 = (g - 512) * 32;  wb = sp;          b1 = B1a; b2 = B2a; b3 = B3a; }
  else               { X = QUERY; outp = Wo; mulx = 0; t0 = (g - 1024) * 32; wb = sp + 196608; b1 = B1b; b2 = B2b; b3 = B3b; }
  const unsigned short* W1h = wb;
  const unsigned short* W1l = wb + 16384;
  const unsigned short* W2h = wb + 32768;
  const unsigned short* W2l = wb + 98304;
  const unsigned short* W3h = wb + 163840;
  const unsigned short* W3l = wb + 180224;

  // ---- stage X tile, split to bf16 h/l ----
  {
    const int t = tid >> 3;
    const int c = (tid & 7) * 8;
    float4 a = *(const float4*)&X[(size_t)(t0 + t) * 64 + c];
    float4 b = *(const float4*)&X[(size_t)(t0 + t) * 64 + c + 4];
    float v[8] = {a.x, a.y, a.z, a.w, b.x, b.y, b.z, b.w};
    unsigned short hs[8], ls[8];
#pragma unroll
    for (int e = 0; e < 8; ++e) splitbf(v[e], hs[e], ls[e]);
    uint4 uh = make_uint4(hs[0] | ((unsigned)hs[1] << 16), hs[2] | ((unsigned)hs[3] << 16),
                          hs[4] | ((unsigned)hs[5] << 16), hs[6] | ((unsigned)hs[7] << 16));
    uint4 ul = make_uint4(ls[0] | ((unsigned)ls[1] << 16), ls[2] | ((unsigned)ls[3] << 16),
                          ls[4] | ((unsigned)ls[5] << 16), ls[6] | ((unsigned)ls[7] << 16));
    *(uint4*)&Xh[t][c] = uh;
    *(uint4*)&Xl[t][c] = ul;
  }
  __syncthreads();

  // ---- layer 1: [32x64] x [64->256] ----
  {
    bf16x8 Ah[2][2], Al[2][2];
#pragma unroll
    for (int mb = 0; mb < 2; ++mb)
#pragma unroll
      for (int kb = 0; kb < 2; ++kb) {
        Ah[mb][kb] = *(const bf16x8*)&Xh[mb * 16 + l15][kb * 32 + quad * 8];
        Al[mb][kb] = *(const bf16x8*)&Xl[mb * 16 + l15][kb * 32 + quad * 8];
      }
    floatx4 acc[2][4];
#pragma unroll
    for (int nb = 0; nb < 4; ++nb) {
      const int n0 = (w * 4 + nb) * 16;
      const float bias = b1[n0 + l15];
      bf16x8 Bh[2], Bl[2];
#pragma unroll
      for (int kb = 0; kb < 2; ++kb) {
        Bh[kb] = *(const bf16x8*)&W1h[(size_t)(n0 + l15) * 64 + kb * 32 + quad * 8];
        Bl[kb] = *(const bf16x8*)&W1l[(size_t)(n0 + l15) * 64 + kb * 32 + quad * 8];
      }
#pragma unroll
      for (int mb = 0; mb < 2; ++mb) acc[mb][nb] = (floatx4){bias, bias, bias, bias};
#pragma unroll
      for (int kb = 0; kb < 2; ++kb)
#pragma unroll
        for (int mb = 0; mb < 2; ++mb) {
          acc[mb][nb] = __builtin_amdgcn_mfma_f32_16x16x32_bf16(Ah[mb][kb], Bh[kb], acc[mb][nb], 0, 0, 0);
          acc[mb][nb] = __builtin_amdgcn_mfma_f32_16x16x32_bf16(Al[mb][kb], Bh[kb], acc[mb][nb], 0, 0, 0);
          acc[mb][nb] = __builtin_amdgcn_mfma_f32_16x16x32_bf16(Ah[mb][kb], Bl[kb], acc[mb][nb], 0, 0, 0);
        }
    }
    // epilogue: relu + split -> H (fresh buffer, disjoint col slices per wave)
#pragma unroll
    for (int mb = 0; mb < 2; ++mb)
#pragma unroll
      for (int nb = 0; nb < 4; ++nb) {
        const int col = (w * 4 + nb) * 16 + l15;
#pragma unroll
        for (int r = 0; r < 4; ++r) {
          const int row = mb * 16 + quad * 4 + r;
          float v = fmaxf(acc[mb][nb][r], 0.0f);
          unsigned short h, l;
          splitbf(v, h, l);
          Hsh[row][col] = h;
          Hsl[row][col] = l;
        }
      }
  }
  __syncthreads();

  // ---- layer 2: [32x256] x [256->256] ----
  floatx4 acc2[2][4];
  {
    bf16x8 Ah[2][8], Al[2][8];
#pragma unroll
    for (int mb = 0; mb < 2; ++mb)
#pragma unroll
      for (int kb = 0; kb < 8; ++kb) {
        Ah[mb][kb] = *(const bf16x8*)&Hsh[mb * 16 + l15][kb * 32 + quad * 8];
        Al[mb][kb] = *(const bf16x8*)&Hsl[mb * 16 + l15][kb * 32 + quad * 8];
      }
#pragma unroll
    for (int nb = 0; nb < 4; ++nb) {
      const int n0 = (w * 4 + nb) * 16;
      const float bias = b2[n0 + l15];
#pragma unroll
      for (int mb = 0; mb < 2; ++mb) acc2[mb][nb] = (floatx4){bias, bias, bias, bias};
      bf16x8 Bh[8];
#pragma unroll
      for (int kb = 0; kb < 8; ++kb)
        Bh[kb] = *(const bf16x8*)&W2h[(size_t)(n0 + l15) * 256 + kb * 32 + quad * 8];
#pragma unroll
      for (int kb = 0; kb < 8; ++kb)
#pragma unroll
        for (int mb = 0; mb < 2; ++mb) {
          acc2[mb][nb] = __builtin_amdgcn_mfma_f32_16x16x32_bf16(Ah[mb][kb], Bh[kb], acc2[mb][nb], 0, 0, 0);
          acc2[mb][nb] = __builtin_amdgcn_mfma_f32_16x16x32_bf16(Al[mb][kb], Bh[kb], acc2[mb][nb], 0, 0, 0);
        }
      bf16x8 Bl[8];
#pragma unroll
      for (int kb = 0; kb < 8; ++kb)
        Bl[kb] = *(const bf16x8*)&W2l[(size_t)(n0 + l15) * 256 + kb * 32 + quad * 8];
#pragma unroll
      for (int kb = 0; kb < 8; ++kb)
#pragma unroll
        for (int mb = 0; mb < 2; ++mb)
          acc2[mb][nb] = __builtin_amdgcn_mfma_f32_16x16x32_bf16(Ah[mb][kb], Bl[kb], acc2[mb][nb], 0, 0, 0);
    }
  }
  __syncthreads();   // all waves done reading h1 -> safe to overwrite H
#pragma unroll
  for (int mb = 0; mb < 2; ++mb)
#pragma unroll
    for (int nb = 0; nb < 4; ++nb) {
      const int col = (w * 4 + nb) * 16 + l15;
#pragma unroll
      for (int r = 0; r < 4; ++r) {
        const int row = mb * 16 + quad * 4 + r;
        float v = fmaxf(acc2[mb][nb][r], 0.0f);
        unsigned short h, l;
        splitbf(v, h, l);
        Hsh[row][col] = h;
        Hsl[row][col] = l;
      }
    }
  __syncthreads();

  // ---- layer 3: [32x256] x [256->64] ----
  {
    bf16x8 Ah[2][8], Al[2][8];
#pragma unroll
    for (int mb = 0; mb < 2; ++mb)
#pragma unroll
      for (int kb = 0; kb < 8; ++kb) {
        Ah[mb][kb] = *(const bf16x8*)&Hsh[mb * 16 + l15][kb * 32 + quad * 8];
        Al[mb][kb] = *(const bf16x8*)&Hsl[mb * 16 + l15][kb * 32 + quad * 8];
      }
    const int n0 = w * 16;
    const float bias = b3[n0 + l15];
    floatx4 acc3[2];
#pragma unroll
    for (int mb = 0; mb < 2; ++mb) acc3[mb] = (floatx4){bias, bias, bias, bias};
    bf16x8 Bh[8], Bl[8];
#pragma unroll
    for (int kb = 0; kb < 8; ++kb) {
      Bh[kb] = *(const bf16x8*)&W3h[(size_t)(n0 + l15) * 256 + kb * 32 + quad * 8];
      Bl[kb] = *(const bf16x8*)&W3l[(size_t)(n0 + l15) * 256 + kb * 32 + quad * 8];
    }
#pragma unroll
    for (int kb = 0; kb < 8; ++kb)
#pragma unroll
      for (int mb = 0; mb < 2; ++mb) {
        acc3[mb] = __builtin_amdgcn_mfma_f32_16x16x32_bf16(Ah[mb][kb], Bh[kb], acc3[mb], 0, 0, 0);
        acc3[mb] = __builtin_amdgcn_mfma_f32_16x16x32_bf16(Al[mb][kb], Bh[kb], acc3[mb], 0, 0, 0);
        acc3[mb] = __builtin_amdgcn_mfma_f32_16x16x32_bf16(Ah[mb][kb], Bl[kb], acc3[mb], 0, 0, 0);
      }
    // epilogue: optional *X, store f32
#pragma unroll
    for (int mb = 0; mb < 2; ++mb)
#pragma unroll
      for (int r = 0; r < 4; ++r) {
        const int row = mb * 16 + quad * 4 + r;
        const int col = n0 + l15;
        float v = acc3[mb][r];
        if (mulx) v *= (bf2f(Xh[row][col]) + bf2f(Xl[row][col]));
        outp[(size_t)(t0 + row) * 64 + col] = v;
      }
  }
}

// ---------------------------------------------------------------------------
// Flash attention over L1-distance scores, P.V on MFMA.
// Round-5 change: score core written as packed float2 ops (pk_sub + pk_max
// with neg for abs + pk_add accumulate -> 1.5 VALU/dim); alpha rescale as
// vector mul (v_pk_mul_f32).
// ---------------------------------------------------------------------------
__global__ __launch_bounds__(256, 2) void attn_kernel(
    const float* __restrict__ Ksg, const float* __restrict__ Qsg,
    const unsigned short* __restrict__ Vtg, const float* __restrict__ Wog,
    float* __restrict__ outp)
{
  __shared__ float qsA[32 * FSTRIDE];
  __shared__ float ksA[4][32 * FSTRIDE];
  __shared__ unsigned short vtB[4][64 * 40];
  __shared__ unsigned short psB[4][32 * 40];
  __shared__ float abA[4][32];
  __shared__ float mbufA[4][32];
  __shared__ float lbufA[4][32];

  const int tid  = threadIdx.x;
  const int w    = tid >> 6;
  const int lane = tid & 63;
  const int lq   = lane >> 3;
  const int lk   = lane & 7;
  const int l15  = lane & 15;
  const int quad = lane >> 4;
  const int b    = blockIdx.y;
  const int qt   = blockIdx.x * 32;

  {
    const int row = tid >> 3;
    const int c0  = (tid & 7) * 2;
    const float4* Q4 = (const float4*)Qsg;
    float4 g0 = Q4[(size_t)(b * NQQ + qt + row) * 16 + c0];
    float4 g1 = Q4[(size_t)(b * NQQ + qt + row) * 16 + c0 + 1];
    *(float4*)&qsA[row * FSTRIDE + c0 * 4]     = g0;
    *(float4*)&qsA[row * FSTRIDE + c0 * 4 + 4] = g1;
  }
  __syncthreads();

  float m_i[4], l_i[4];
  floatx4 acc[2][4];
#pragma unroll
  for (int i = 0; i < 4; ++i) { m_i[i] = -3.0e38f; l_i[i] = 0.0f; }
#pragma unroll
  for (int mb = 0; mb < 2; ++mb)
#pragma unroll
    for (int nb = 0; nb < 4; ++nb)
#pragma unroll
      for (int r = 0; r < 4; ++r) acc[mb][nb][r] = 0.0f;

  const int kstart = w * (NKK / 4);
  const float4* K4 = (const float4*)Ksg;
  const unsigned short* vg = Vtg + ((size_t)b * 64 + lane) * NKK + kstart;
  const float NEG_HALF_LOG2E = -0.72134752044448170f;

  const int krow = (lane >> 4);
  const int kci  = lane & 15;
  const int vst  = (lane >> 3) & 3;

  float4 kpre[8];
  uint4 vtpre[4];
#pragma unroll
  for (int c = 0; c < 8; ++c)
    kpre[c] = K4[(size_t)(b * NKK + kstart + c * 4 + krow) * 16 + kci];
#pragma unroll
  for (int c = 0; c < 4; ++c)
    vtpre[c] = *(const uint4*)(vg + c * 8);

  const floatx4* qb = (const floatx4*)&qsA[lq * FSTRIDE];
  const floatx4* kb = (const floatx4*)&ksA[w][lk * FSTRIDE];

  int vcol[4];
#pragma unroll
  for (int nb = 0; nb < 4; ++nb)
    vcol[nb] = (((quad + (l15 >> 3) + 2 * nb) & 3) << 3);

  for (int it = 0; it < (NKK / 4) / 32; ++it) {
#pragma unroll
    for (int c = 0; c < 8; ++c)
      *(float4*)&ksA[w][(c * 4 + krow) * FSTRIDE + kci * 4] = kpre[c];
#pragma unroll
    for (int c = 0; c < 4; ++c)
      *(uint4*)&vtB[w][lane * 40 + (((c + vst) & 3) << 3)] = vtpre[c];

    {
      const int itn = (it + 1 < 32) ? it + 1 : it;
#pragma unroll
      for (int c = 0; c < 8; ++c)
        kpre[c] = K4[(size_t)(b * NKK + kstart + itn * 32 + c * 4 + krow) * 16 + kci];
#pragma unroll
      for (int c = 0; c < 4; ++c)
        vtpre[c] = *(const uint4*)(vg + itn * 32 + c * 8);
    }

    // ---- score: packed f32 core, 3 pk-ops per 2 dims ----
    floatx2 s2[4][4];
#pragma unroll
    for (int i = 0; i < 4; ++i)
#pragma unroll
      for (int j = 0; j < 4; ++j) s2[i][j] = (floatx2){0.0f, 0.0f};

#pragma unroll
    for (int dc = 0; dc < 16; ++dc) {
      floatx4 qv[4], kv[4];
#pragma unroll
      for (int i = 0; i < 4; ++i) qv[i] = qb[i * (8 * FSTRIDE4) + dc];
#pragma unroll
      for (int j = 0; j < 4; ++j) kv[j] = kb[j * (8 * FSTRIDE4) + dc];
#pragma unroll
      for (int i = 0; i < 4; ++i) {
        const floatx2 qlo = qv[i].lo, qhi = qv[i].hi;
#pragma unroll
        for (int j = 0; j < 4; ++j) {
          floatx2 d0 = qlo - kv[j].lo;
          floatx2 d1 = qhi - kv[j].hi;
          s2[i][j] += __builtin_elementwise_max(d0, -d0);
          s2[i][j] += __builtin_elementwise_max(d1, -d1);
        }
      }
    }

    // ---- online softmax (base-2); row max via min(s); l per-lane ----
    float a_row[4];
#pragma unroll
    for (int i = 0; i < 4; ++i) {
      float s[4];
#pragma unroll
      for (int j = 0; j < 4; ++j) s[j] = s2[i][j].x + s2[i][j].y;
      float smin = fminf(fminf(s[0], s[1]), fminf(s[2], s[3]));
      smin = fminf(smin, __shfl_xor(smin, 1));
      smin = fminf(smin, __shfl_xor(smin, 2));
      smin = fminf(smin, __shfl_xor(smin, 4));
      const float tmax = smin * smin * NEG_HALF_LOG2E;
      const float mn = fmaxf(m_i[i], tmax);
      a_row[i] = fexp2(m_i[i] - mn);
      m_i[i] = mn;
      float ps = 0.0f;
#pragma unroll
      for (int j = 0; j < 4; ++j) {
        const float sv = s[j];
        const float e = fexp2(fmaf(sv * NEG_HALF_LOG2E, sv, -mn));
        ps += e;
        psB[w][(lq + 8 * i) * 40 + lk + 8 * j] = (unsigned short)(fbits(e) >> 16);
      }
      l_i[i] = fmaf(l_i[i], a_row[i], ps);
    }
    if (lk == 0) {
#pragma unroll
      for (int i = 0; i < 4; ++i) abA[w][lq + 8 * i] = a_row[i];
    }

    // ---- P.V on MFMA ----
    {
      bf16x8 afrag[2], bfrag[4];
#pragma unroll
      for (int mb = 0; mb < 2; ++mb)
        afrag[mb] = *(const bf16x8*)&psB[w][(mb * 16 + l15) * 40 + quad * 8];
#pragma unroll
      for (int nb = 0; nb < 4; ++nb)
        bfrag[nb] = *(const bf16x8*)&vtB[w][(nb * 16 + l15) * 40 + vcol[nb]];

      const floatx4 arv0 = *(const floatx4*)&abA[w][quad * 4];
      const floatx4 arv1 = *(const floatx4*)&abA[w][16 + quad * 4];

#pragma unroll
      for (int nb = 0; nb < 4; ++nb) {
        acc[0][nb] *= arv0;
        acc[1][nb] *= arv1;
        acc[0][nb] = __builtin_amdgcn_mfma_f32_16x16x32_bf16(afrag[0], bfrag[nb], acc[0][nb], 0, 0, 0);
        acc[1][nb] = __builtin_amdgcn_mfma_f32_16x16x32_bf16(afrag[1], bfrag[nb], acc[1][nb], 0, 0, 0);
      }
    }
  }

  // ---- epilogue ----
#pragma unroll
  for (int i = 0; i < 4; ++i) {
    float l = l_i[i];
    l += __shfl_xor(l, 1);
    l += __shfl_xor(l, 2);
    l += __shfl_xor(l, 4);
    l_i[i] = l;
  }
  if (lk == 0) {
#pragma unroll
    for (int i = 0; i < 4; ++i) {
      mbufA[w][lq + 8 * i] = m_i[i];
      lbufA[w][lq + 8 * i] = l_i[i];
    }
  }
#pragma unroll
  for (int mb = 0; mb < 2; ++mb)
#pragma unroll
    for (int nb = 0; nb < 4; ++nb)
#pragma unroll
      for (int r = 0; r < 4; ++r)
        ksA[w][(mb * 16 + quad * 4 + r) * 64 + nb * 16 + l15] = acc[mb][nb][r];
  __syncthreads();

  {
    const int q = tid >> 3;
    const int dbase = (tid & 7) * 8;
    const float m0 = mbufA[0][q], m1 = mbufA[1][q], m2 = mbufA[2][q], m3 = mbufA[3][q];
    const float M = fmaxf(fmaxf(m0, m1), fmaxf(m2, m3));
    const float s0 = fexp2(m0 - M), s1 = fexp2(m1 - M);
    const float s2v = fexp2(m2 - M), s3 = fexp2(m3 - M);
    const float L = lbufA[0][q] * s0 + lbufA[1][q] * s1 + lbufA[2][q] * s2v + lbufA[3][q] * s3;
    const float rL = 1.0f / L;
    const size_t gbase = (size_t)(b * NQQ + qt + q) * 64 + dbase;
#pragma unroll
    for (int c = 0; c < 8; ++c) {
      const int d = dbase + c;
      float o = s0 * ksA[0][q * 64 + d] + s1 * ksA[1][q * 64 + d] +
                s2v * ksA[2][q * 64 + d] + s3 * ksA[3][q * 64 + d];
      outp[gbase + c] = o * rL * Wog[gbase + c];
    }
  }
}

// ---------------------------------------------------------------------------
extern "C" void kernel_launch(void* const* d_in, const int* in_sizes, int n_in,
                              void* d_out, int out_size, void* d_ws, size_t ws_size,
                              hipStream_t stream) {
  (void)in_sizes; (void)n_in; (void)out_size; (void)ws_size;
  const float* KEY   = (const float*)d_in[0];
  const float* VALUE = (const float*)d_in[1];
  const float* QUERY = (const float*)d_in[2];
  const float* W1w = (const float*)d_in[3];
  const float* W1b = (const float*)d_in[4];
  const float* W2w = (const float*)d_in[5];
  const float* W2b = (const float*)d_in[6];
  const float* W3w = (const float*)d_in[7];
  const float* W3b = (const float*)d_in[8];
  const float* Wo1w = (const float*)d_in[9];
  const float* Wo1b = (const float*)d_in[10];
  const float* Wo2w = (const float*)d_in[11];
  const float* Wo2b = (const float*)d_in[12];
  const float* Wo3w = (const float*)d_in[13];
  const float* Wo3b = (const float*)d_in[14];

  float* ws = (float*)d_ws;
  const size_t tsz = (size_t)B_DIM * NKK * DD;  // 1M floats
  float* Ks = ws;
  float* Qs = ws + tsz;
  float* Wo = ws + 2 * tsz;
  unsigned short* Vtg = (unsigned short*)(ws + 3 * tsz);  // 2 MB bf16
  unsigned short* sp  = Vtg + tsz;                        // split weights, 768 KB
  float* outf = (float*)d_out;

  wsplit_kernel<<<dim3(768), 256, 0, stream>>>(W1w, W2w, W3w, Wo1w, Wo2w, Wo3w, sp);
  vtrans_kernel<<<dim3(NKK / 64, B_DIM), 256, 0, stream>>>(VALUE, Vtg);
  mlpmm_kernel<<<dim3(1536), 256, 0, stream>>>(
      KEY, QUERY, W1b, W2b, W3b, Wo1b, Wo2b, Wo3b, sp, Ks, Qs, Wo);
  attn_kernel<<<dim3(NQQ / 32, B_DIM), 256, 0, stream>>>(Ks, Qs, Vtg, Wo, outf);
}

// Round 6
// 433.584 us; speedup vs baseline: 1.8764x; 1.2063x over previous
//
#include <hip/hip_runtime.h>
#include <hip/hip_bf16.h>
#include <stdint.h>

#define B_DIM 4
#define NKK 4096
#define NQQ 4096
#define DD 64
#define HH 256

typedef __attribute__((ext_vector_type(4))) float floatx4;
typedef __attribute__((ext_vector_type(2))) float floatx2;
typedef __attribute__((ext_vector_type(8))) short bf16x8;

__device__ __forceinline__ float fexp2(float x) { return __builtin_amdgcn_exp2f(x); }
__device__ __forceinline__ unsigned fbits(float x) { return __float_as_uint(x); }
__device__ __forceinline__ float bf2f(unsigned short u) { return __uint_as_float(((unsigned)u) << 16); }

// a - b on both packed halves in ONE VOP3P instruction (gfx950 has
// v_pk_add_f32 but no packed max/abs -- so abs lives on the consumer's
// input modifier instead).
__device__ __forceinline__ floatx2 pk_sub(floatx2 a, floatx2 b) {
  floatx2 d;
  asm("v_pk_add_f32 %0, %1, %2 neg_lo:[0,1] neg_hi:[0,1]" : "=v"(d) : "v"(a), "v"(b));
  return d;
}

// round-to-nearest-even split: x = h + l, h/l bf16, rel err ~2^-17
__device__ __forceinline__ void splitbf(float x, unsigned short& h, unsigned short& l) {
  unsigned u = fbits(x);
  unsigned hu = (u + 0x7fff + ((u >> 16) & 1)) & 0xffff0000u;
  h = (unsigned short)(hu >> 16);
  l = (unsigned short)(fbits(x - __uint_as_float(hu)) >> 16);
}

// f32 LDS tile row stride (floats): bank-start 4r mod 32, 8 consecutive rows
// -> 8 distinct bank-quads -> conflict-free (verified round 4: 33.9M -> 2.85M).
#define FSTRIDE 68
#define FSTRIDE4 17

// ---------------------------------------------------------------------------
// Weight split prep: per set {W1[256x64], W2[256x256], W3[64x256]} write
// h/l bf16 arrays. Set0 = (W1,W2,W3), set1 = (Wo1,Wo2,Wo3).
// ---------------------------------------------------------------------------
__global__ __launch_bounds__(256) void wsplit_kernel(
    const float* __restrict__ W1a, const float* __restrict__ W2a, const float* __restrict__ W3a,
    const float* __restrict__ W1b, const float* __restrict__ W2b, const float* __restrict__ W3b,
    unsigned short* __restrict__ sp)
{
  int idx = blockIdx.x * 256 + threadIdx.x;       // 0..196607
  const int set = idx >= 98304;
  int r = idx - set * 98304;
  unsigned short* base = sp + (size_t)set * 196608;
  const float* src;
  unsigned short *dh, *dl;
  int j;
  if (r < 16384)      { src = set ? W1b : W1a; dh = base;          dl = base + 16384;  j = r; }
  else if (r < 81920) { src = set ? W2b : W2a; dh = base + 32768;  dl = base + 98304;  j = r - 16384; }
  else                { src = set ? W3b : W3a; dh = base + 163840; dl = base + 180224; j = r - 81920; }
  unsigned short h, l;
  splitbf(src[j], h, l);
  dh[j] = h; dl[j] = l;
}

// ---------------------------------------------------------------------------
// V pre-transpose: Vt[b][d][k] = bf16(V[b][k][d]).
// ---------------------------------------------------------------------------
__global__ __launch_bounds__(256) void vtrans_kernel(
    const float* __restrict__ V, unsigned short* __restrict__ Vt)
{
  __shared__ unsigned short t[64][80];
  const int tid = threadIdx.x;
  const int b = blockIdx.y;
  const int k0 = blockIdx.x * 64;
  const float4* V4 = (const float4*)V;
  {
    const int r = tid & 63;
    const int c4 = tid >> 6;
#pragma unroll
    for (int j = 0; j < 4; ++j) {
      float4 f = V4[((size_t)(b * NKK + k0 + r)) * 16 + c4 * 4 + j];
      const int d0 = c4 * 16 + j * 4;
      t[d0 + 0][r] = (unsigned short)(fbits(f.x) >> 16);
      t[d0 + 1][r] = (unsigned short)(fbits(f.y) >> 16);
      t[d0 + 2][r] = (unsigned short)(fbits(f.z) >> 16);
      t[d0 + 3][r] = (unsigned short)(fbits(f.w) >> 16);
    }
  }
  __syncthreads();
  {
    const int d = tid >> 2;
    const int kc = tid & 3;
    uint4 u0 = *(const uint4*)&t[d][kc * 16];
    uint4 u1 = *(const uint4*)&t[d][kc * 16 + 8];
    unsigned short* dst = Vt + ((size_t)(b * 64 + d)) * NKK + k0 + kc * 16;
    *(uint4*)dst = u0;
    *(uint4*)(dst + 8) = u1;
  }
}

// ---------------------------------------------------------------------------
// MLP on MFMA, split-bf16 (hh+lh+hl). Round-6: 64 tokens/WG, 512 threads
// (8 waves) -- halves the per-token weight re-read from L2, which dominated
// the 32-token version (~90us vs ~17us L2-BW floor). LDS 84 KB -> 1 WG/CU
// x 8 waves = same waves/CU as before.
// Wave w owns output-channel blocks {w*2, w*2+1} (x16) in L1/L2; in L3,
// wave w does col-block (w&3), row-half (w>>2).
// ---------------------------------------------------------------------------
#define HSTRIDE 264   // shorts; 528B = 132 dwords = 4 mod 32 -> 2-way (free)
__global__ __launch_bounds__(512, 1) void mlpmm_kernel(
    const float* __restrict__ KEY, const float* __restrict__ QUERY,
    const float* __restrict__ B1a, const float* __restrict__ B2a, const float* __restrict__ B3a,
    const float* __restrict__ B1b, const float* __restrict__ B2b, const float* __restrict__ B3b,
    const unsigned short* __restrict__ sp,
    float* __restrict__ Ks, float* __restrict__ Qs, float* __restrict__ Wo)
{
  __shared__ unsigned short Xh[64][72], Xl[64][72];             // 18 KB
  __shared__ unsigned short Hsh[64][HSTRIDE], Hsl[64][HSTRIDE]; // 66 KB
  const int tid = threadIdx.x;
  const int w = tid >> 6;        // 0..7
  const int lane = tid & 63;
  const int l15 = lane & 15;
  const int quad = lane >> 4;

  const int g = blockIdx.x;
  const float* X;
  float* outp;
  int mulx, t0;
  const unsigned short* wb;
  const float *b1, *b2, *b3;
  if (g < 256)      { X = KEY;   outp = Ks; mulx = 1; t0 = g * 64;         wb = sp;          b1 = B1a; b2 = B2a; b3 = B3a; }
  else if (g < 512) { X = QUERY; outp = Qs; mulx = 1; t0 = (g - 256) * 64; wb = sp;          b1 = B1a; b2 = B2a; b3 = B3a; }
  else              { X = QUERY; outp = Wo; mulx = 0; t0 = (g - 512) * 64; wb = sp + 196608; b1 = B1b; b2 = B2b; b3 = B3b; }
  const unsigned short* W1h = wb;
  const unsigned short* W1l = wb + 16384;
  const unsigned short* W2h = wb + 32768;
  const unsigned short* W2l = wb + 98304;
  const unsigned short* W3h = wb + 163840;
  const unsigned short* W3l = wb + 180224;

  // ---- stage X tile (64 rows), split to bf16 h/l ----
  {
    const int t = tid >> 3;
    const int c = (tid & 7) * 8;
    float4 a = *(const float4*)&X[(size_t)(t0 + t) * 64 + c];
    float4 b = *(const float4*)&X[(size_t)(t0 + t) * 64 + c + 4];
    float v[8] = {a.x, a.y, a.z, a.w, b.x, b.y, b.z, b.w};
    unsigned short hs[8], ls[8];
#pragma unroll
    for (int e = 0; e < 8; ++e) splitbf(v[e], hs[e], ls[e]);
    uint4 uh = make_uint4(hs[0] | ((unsigned)hs[1] << 16), hs[2] | ((unsigned)hs[3] << 16),
                          hs[4] | ((unsigned)hs[5] << 16), hs[6] | ((unsigned)hs[7] << 16));
    uint4 ul = make_uint4(ls[0] | ((unsigned)ls[1] << 16), ls[2] | ((unsigned)ls[3] << 16),
                          ls[4] | ((unsigned)ls[5] << 16), ls[6] | ((unsigned)ls[7] << 16));
    *(uint4*)&Xh[t][c] = uh;
    *(uint4*)&Xl[t][c] = ul;
  }
  __syncthreads();

  // ---- layer 1: [64x64] x [64->256] ----
  {
    floatx4 acc[4][2];
#pragma unroll
    for (int nb = 0; nb < 2; ++nb) {
      const float bias = b1[(w * 2 + nb) * 16 + l15];
#pragma unroll
      for (int mb = 0; mb < 4; ++mb) acc[mb][nb] = (floatx4){bias, bias, bias, bias};
    }
#pragma unroll
    for (int kb = 0; kb < 2; ++kb) {
      bf16x8 Ah[4], Al[4];
#pragma unroll
      for (int mb = 0; mb < 4; ++mb) {
        Ah[mb] = *(const bf16x8*)&Xh[mb * 16 + l15][kb * 32 + quad * 8];
        Al[mb] = *(const bf16x8*)&Xl[mb * 16 + l15][kb * 32 + quad * 8];
      }
#pragma unroll
      for (int nb = 0; nb < 2; ++nb) {
        const int n0 = (w * 2 + nb) * 16;
        bf16x8 Bh = *(const bf16x8*)&W1h[(size_t)(n0 + l15) * 64 + kb * 32 + quad * 8];
        bf16x8 Bl = *(const bf16x8*)&W1l[(size_t)(n0 + l15) * 64 + kb * 32 + quad * 8];
#pragma unroll
        for (int mb = 0; mb < 4; ++mb) {
          acc[mb][nb] = __builtin_amdgcn_mfma_f32_16x16x32_bf16(Ah[mb], Bh, acc[mb][nb], 0, 0, 0);
          acc[mb][nb] = __builtin_amdgcn_mfma_f32_16x16x32_bf16(Al[mb], Bh, acc[mb][nb], 0, 0, 0);
          acc[mb][nb] = __builtin_amdgcn_mfma_f32_16x16x32_bf16(Ah[mb], Bl, acc[mb][nb], 0, 0, 0);
        }
      }
    }
#pragma unroll
    for (int mb = 0; mb < 4; ++mb)
#pragma unroll
      for (int nb = 0; nb < 2; ++nb) {
        const int col = (w * 2 + nb) * 16 + l15;
#pragma unroll
        for (int r = 0; r < 4; ++r) {
          const int row = mb * 16 + quad * 4 + r;
          float v = fmaxf(acc[mb][nb][r], 0.0f);
          unsigned short h, l;
          splitbf(v, h, l);
          Hsh[row][col] = h;
          Hsl[row][col] = l;
        }
      }
  }
  __syncthreads();

  // ---- layer 2: [64x256] x [256->256] ----
  {
    floatx4 acc2[4][2];
#pragma unroll
    for (int nb = 0; nb < 2; ++nb) {
      const float bias = b2[(w * 2 + nb) * 16 + l15];
#pragma unroll
      for (int mb = 0; mb < 4; ++mb) acc2[mb][nb] = (floatx4){bias, bias, bias, bias};
    }
#pragma unroll
    for (int kb = 0; kb < 8; ++kb) {
      bf16x8 Ah[4], Al[4];
#pragma unroll
      for (int mb = 0; mb < 4; ++mb) {
        Ah[mb] = *(const bf16x8*)&Hsh[mb * 16 + l15][kb * 32 + quad * 8];
        Al[mb] = *(const bf16x8*)&Hsl[mb * 16 + l15][kb * 32 + quad * 8];
      }
#pragma unroll
      for (int nb = 0; nb < 2; ++nb) {
        const int n0 = (w * 2 + nb) * 16;
        bf16x8 Bh = *(const bf16x8*)&W2h[(size_t)(n0 + l15) * 256 + kb * 32 + quad * 8];
        bf16x8 Bl = *(const bf16x8*)&W2l[(size_t)(n0 + l15) * 256 + kb * 32 + quad * 8];
#pragma unroll
        for (int mb = 0; mb < 4; ++mb) {
          acc2[mb][nb] = __builtin_amdgcn_mfma_f32_16x16x32_bf16(Ah[mb], Bh, acc2[mb][nb], 0, 0, 0);
          acc2[mb][nb] = __builtin_amdgcn_mfma_f32_16x16x32_bf16(Al[mb], Bh, acc2[mb][nb], 0, 0, 0);
          acc2[mb][nb] = __builtin_amdgcn_mfma_f32_16x16x32_bf16(Ah[mb], Bl, acc2[mb][nb], 0, 0, 0);
        }
      }
    }
    __syncthreads();   // all waves done reading h1 -> safe to overwrite H
#pragma unroll
    for (int mb = 0; mb < 4; ++mb)
#pragma unroll
      for (int nb = 0; nb < 2; ++nb) {
        const int col = (w * 2 + nb) * 16 + l15;
#pragma unroll
        for (int r = 0; r < 4; ++r) {
          const int row = mb * 16 + quad * 4 + r;
          float v = fmaxf(acc2[mb][nb][r], 0.0f);
          unsigned short h, l;
          splitbf(v, h, l);
          Hsh[row][col] = h;
          Hsl[row][col] = l;
        }
      }
  }
  __syncthreads();

  // ---- layer 3: [64x256] x [256->64] ----
  {
    const int mp = (w >> 2) * 2;   // row-half: mb = mp, mp+1
    const int n0 = (w & 3) * 16;   // col block
    const float bias = b3[n0 + l15];
    floatx4 acc3[2];
#pragma unroll
    for (int m = 0; m < 2; ++m) acc3[m] = (floatx4){bias, bias, bias, bias};
#pragma unroll
    for (int kb = 0; kb < 8; ++kb) {
      bf16x8 Ah[2], Al[2];
#pragma unroll
      for (int m = 0; m < 2; ++m) {
        Ah[m] = *(const bf16x8*)&Hsh[(mp + m) * 16 + l15][kb * 32 + quad * 8];
        Al[m] = *(const bf16x8*)&Hsl[(mp + m) * 16 + l15][kb * 32 + quad * 8];
      }
      bf16x8 Bh = *(const bf16x8*)&W3h[(size_t)(n0 + l15) * 256 + kb * 32 + quad * 8];
      bf16x8 Bl = *(const bf16x8*)&W3l[(size_t)(n0 + l15) * 256 + kb * 32 + quad * 8];
#pragma unroll
      for (int m = 0; m < 2; ++m) {
        acc3[m] = __builtin_amdgcn_mfma_f32_16x16x32_bf16(Ah[m], Bh, acc3[m], 0, 0, 0);
        acc3[m] = __builtin_amdgcn_mfma_f32_16x16x32_bf16(Al[m], Bh, acc3[m], 0, 0, 0);
        acc3[m] = __builtin_amdgcn_mfma_f32_16x16x32_bf16(Ah[m], Bl, acc3[m], 0, 0, 0);
      }
    }
#pragma unroll
    for (int m = 0; m < 2; ++m)
#pragma unroll
      for (int r = 0; r < 4; ++r) {
        const int row = (mp + m) * 16 + quad * 4 + r;
        const int col = n0 + l15;
        float v = acc3[m][r];
        if (mulx) v *= (bf2f(Xh[row][col]) + bf2f(Xl[row][col]));
        outp[(size_t)(t0 + row) * 64 + col] = v;
      }
  }
}

// ---------------------------------------------------------------------------
// Flash attention over L1-distance scores, P.V on MFMA.
// Round-6 score core: one v_pk_add_f32 (neg) per 2 dims + 2 scalar adds with
// |abs| input modifiers = 1.5 VALU/dim (round-4 was 2, round-5's
// elementwise_max form scalarized to 3 -- no packed f32 max on gfx950).
// ---------------------------------------------------------------------------
__global__ __launch_bounds__(256, 2) void attn_kernel(
    const float* __restrict__ Ksg, const float* __restrict__ Qsg,
    const unsigned short* __restrict__ Vtg, const float* __restrict__ Wog,
    float* __restrict__ outp)
{
  __shared__ float qsA[32 * FSTRIDE];
  __shared__ float ksA[4][32 * FSTRIDE];
  __shared__ unsigned short vtB[4][64 * 40];
  __shared__ unsigned short psB[4][32 * 40];
  __shared__ float abA[4][32];
  __shared__ float mbufA[4][32];
  __shared__ float lbufA[4][32];

  const int tid  = threadIdx.x;
  const int w    = tid >> 6;
  const int lane = tid & 63;
  const int lq   = lane >> 3;
  const int lk   = lane & 7;
  const int l15  = lane & 15;
  const int quad = lane >> 4;
  const int b    = blockIdx.y;
  const int qt   = blockIdx.x * 32;

  {
    const int row = tid >> 3;
    const int c0  = (tid & 7) * 2;
    const float4* Q4 = (const float4*)Qsg;
    float4 g0 = Q4[(size_t)(b * NQQ + qt + row) * 16 + c0];
    float4 g1 = Q4[(size_t)(b * NQQ + qt + row) * 16 + c0 + 1];
    *(float4*)&qsA[row * FSTRIDE + c0 * 4]     = g0;
    *(float4*)&qsA[row * FSTRIDE + c0 * 4 + 4] = g1;
  }
  __syncthreads();

  float m_i[4], l_i[4];
  floatx4 acc[2][4];
#pragma unroll
  for (int i = 0; i < 4; ++i) { m_i[i] = -3.0e38f; l_i[i] = 0.0f; }
#pragma unroll
  for (int mb = 0; mb < 2; ++mb)
#pragma unroll
    for (int nb = 0; nb < 4; ++nb)
#pragma unroll
      for (int r = 0; r < 4; ++r) acc[mb][nb][r] = 0.0f;

  const int kstart = w * (NKK / 4);
  const float4* K4 = (const float4*)Ksg;
  const unsigned short* vg = Vtg + ((size_t)b * 64 + lane) * NKK + kstart;
  const float NEG_HALF_LOG2E = -0.72134752044448170f;

  const int krow = (lane >> 4);
  const int kci  = lane & 15;
  const int vst  = (lane >> 3) & 3;

  float4 kpre[8];
  uint4 vtpre[4];
#pragma unroll
  for (int c = 0; c < 8; ++c)
    kpre[c] = K4[(size_t)(b * NKK + kstart + c * 4 + krow) * 16 + kci];
#pragma unroll
  for (int c = 0; c < 4; ++c)
    vtpre[c] = *(const uint4*)(vg + c * 8);

  const floatx4* qb = (const floatx4*)&qsA[lq * FSTRIDE];
  const floatx4* kb = (const floatx4*)&ksA[w][lk * FSTRIDE];

  int vcol[4];
#pragma unroll
  for (int nb = 0; nb < 4; ++nb)
    vcol[nb] = (((quad + (l15 >> 3) + 2 * nb) & 3) << 3);

  for (int it = 0; it < (NKK / 4) / 32; ++it) {
#pragma unroll
    for (int c = 0; c < 8; ++c)
      *(float4*)&ksA[w][(c * 4 + krow) * FSTRIDE + kci * 4] = kpre[c];
#pragma unroll
    for (int c = 0; c < 4; ++c)
      *(uint4*)&vtB[w][lane * 40 + (((c + vst) & 3) << 3)] = vtpre[c];

    {
      const int itn = (it + 1 < 32) ? it + 1 : it;
#pragma unroll
      for (int c = 0; c < 8; ++c)
        kpre[c] = K4[(size_t)(b * NKK + kstart + itn * 32 + c * 4 + krow) * 16 + kci];
#pragma unroll
      for (int c = 0; c < 4; ++c)
        vtpre[c] = *(const uint4*)(vg + itn * 32 + c * 8);
    }

    // ---- score: s[i][j] = sum_d |Ks[lk+8j] - Qs[lq+8i]|, 1.5 VALU/dim ----
    float s[4][4];
#pragma unroll
    for (int i = 0; i < 4; ++i)
#pragma unroll
      for (int j = 0; j < 4; ++j) s[i][j] = 0.0f;

#pragma unroll
    for (int dc = 0; dc < 16; ++dc) {
      floatx4 qv[4], kv[4];
#pragma unroll
      for (int i = 0; i < 4; ++i) qv[i] = qb[i * (8 * FSTRIDE4) + dc];
#pragma unroll
      for (int j = 0; j < 4; ++j) kv[j] = kb[j * (8 * FSTRIDE4) + dc];
#pragma unroll
      for (int i = 0; i < 4; ++i) {
        const floatx2 qlo = qv[i].lo, qhi = qv[i].hi;
#pragma unroll
        for (int j = 0; j < 4; ++j) {
          floatx2 d0 = pk_sub(qlo, kv[j].lo);
          floatx2 d1 = pk_sub(qhi, kv[j].hi);
          s[i][j] += __builtin_fabsf(d0.x);
          s[i][j] += __builtin_fabsf(d0.y);
          s[i][j] += __builtin_fabsf(d1.x);
          s[i][j] += __builtin_fabsf(d1.y);
        }
      }
    }

    // ---- online softmax (base-2); row max via min(s); l per-lane ----
    float a_row[4];
#pragma unroll
    for (int i = 0; i < 4; ++i) {
      float smin = fminf(fminf(s[i][0], s[i][1]), fminf(s[i][2], s[i][3]));
      smin = fminf(smin, __shfl_xor(smin, 1));
      smin = fminf(smin, __shfl_xor(smin, 2));
      smin = fminf(smin, __shfl_xor(smin, 4));
      const float tmax = smin * smin * NEG_HALF_LOG2E;
      const float mn = fmaxf(m_i[i], tmax);
      a_row[i] = fexp2(m_i[i] - mn);
      m_i[i] = mn;
      float ps = 0.0f;
#pragma unroll
      for (int j = 0; j < 4; ++j) {
        const float sv = s[i][j];
        const float e = fexp2(fmaf(sv * NEG_HALF_LOG2E, sv, -mn));
        ps += e;
        psB[w][(lq + 8 * i) * 40 + lk + 8 * j] = (unsigned short)(fbits(e) >> 16);
      }
      l_i[i] = fmaf(l_i[i], a_row[i], ps);
    }
    if (lk == 0) {
#pragma unroll
      for (int i = 0; i < 4; ++i) abA[w][lq + 8 * i] = a_row[i];
    }

    // ---- P.V on MFMA ----
    {
      bf16x8 afrag[2], bfrag[4];
#pragma unroll
      for (int mb = 0; mb < 2; ++mb)
        afrag[mb] = *(const bf16x8*)&psB[w][(mb * 16 + l15) * 40 + quad * 8];
#pragma unroll
      for (int nb = 0; nb < 4; ++nb)
        bfrag[nb] = *(const bf16x8*)&vtB[w][(nb * 16 + l15) * 40 + vcol[nb]];

      const floatx4 arv0 = *(const floatx4*)&abA[w][quad * 4];
      const floatx4 arv1 = *(const floatx4*)&abA[w][16 + quad * 4];

#pragma unroll
      for (int nb = 0; nb < 4; ++nb) {
        acc[0][nb] *= arv0;
        acc[1][nb] *= arv1;
        acc[0][nb] = __builtin_amdgcn_mfma_f32_16x16x32_bf16(afrag[0], bfrag[nb], acc[0][nb], 0, 0, 0);
        acc[1][nb] = __builtin_amdgcn_mfma_f32_16x16x32_bf16(afrag[1], bfrag[nb], acc[1][nb], 0, 0, 0);
      }
    }
  }

  // ---- epilogue ----
#pragma unroll
  for (int i = 0; i < 4; ++i) {
    float l = l_i[i];
    l += __shfl_xor(l, 1);
    l += __shfl_xor(l, 2);
    l += __shfl_xor(l, 4);
    l_i[i] = l;
  }
  if (lk == 0) {
#pragma unroll
    for (int i = 0; i < 4; ++i) {
      mbufA[w][lq + 8 * i] = m_i[i];
      lbufA[w][lq + 8 * i] = l_i[i];
    }
  }
#pragma unroll
  for (int mb = 0; mb < 2; ++mb)
#pragma unroll
    for (int nb = 0; nb < 4; ++nb)
#pragma unroll
      for (int r = 0; r < 4; ++r)
        ksA[w][(mb * 16 + quad * 4 + r) * 64 + nb * 16 + l15] = acc[mb][nb][r];
  __syncthreads();

  {
    const int q = tid >> 3;
    const int dbase = (tid & 7) * 8;
    const float m0 = mbufA[0][q], m1 = mbufA[1][q], m2 = mbufA[2][q], m3 = mbufA[3][q];
    const float M = fmaxf(fmaxf(m0, m1), fmaxf(m2, m3));
    const float s0 = fexp2(m0 - M), s1 = fexp2(m1 - M);
    const float s2v = fexp2(m2 - M), s3 = fexp2(m3 - M);
    const float L = lbufA[0][q] * s0 + lbufA[1][q] * s1 + lbufA[2][q] * s2v + lbufA[3][q] * s3;
    const float rL = 1.0f / L;
    const size_t gbase = (size_t)(b * NQQ + qt + q) * 64 + dbase;
#pragma unroll
    for (int c = 0; c < 8; ++c) {
      const int d = dbase + c;
      float o = s0 * ksA[0][q * 64 + d] + s1 * ksA[1][q * 64 + d] +
                s2v * ksA[2][q * 64 + d] + s3 * ksA[3][q * 64 + d];
      outp[gbase + c] = o * rL * Wog[gbase + c];
    }
  }
}

// ---------------------------------------------------------------------------
extern "C" void kernel_launch(void* const* d_in, const int* in_sizes, int n_in,
                              void* d_out, int out_size, void* d_ws, size_t ws_size,
                              hipStream_t stream) {
  (void)in_sizes; (void)n_in; (void)out_size; (void)ws_size;
  const float* KEY   = (const float*)d_in[0];
  const float* VALUE = (const float*)d_in[1];
  const float* QUERY = (const float*)d_in[2];
  const float* W1w = (const float*)d_in[3];
  const float* W1b = (const float*)d_in[4];
  const float* W2w = (const float*)d_in[5];
  const float* W2b = (const float*)d_in[6];
  const float* W3w = (const float*)d_in[7];
  const float* W3b = (const float*)d_in[8];
  const float* Wo1w = (const float*)d_in[9];
  const float* Wo1b = (const float*)d_in[10];
  const float* Wo2w = (const float*)d_in[11];
  const float* Wo2b = (const float*)d_in[12];
  const float* Wo3w = (const float*)d_in[13];
  const float* Wo3b = (const float*)d_in[14];

  float* ws = (float*)d_ws;
  const size_t tsz = (size_t)B_DIM * NKK * DD;  // 1M floats
  float* Ks = ws;
  float* Qs = ws + tsz;
  float* Wo = ws + 2 * tsz;
  unsigned short* Vtg = (unsigned short*)(ws + 3 * tsz);  // 2 MB bf16
  unsigned short* sp  = Vtg + tsz;                        // split weights, 768 KB
  float* outf = (float*)d_out;

  wsplit_kernel<<<dim3(768), 256, 0, stream>>>(W1w, W2w, W3w, Wo1w, Wo2w, Wo3w, sp);
  vtrans_kernel<<<dim3(NKK / 64, B_DIM), 256, 0, stream>>>(VALUE, Vtg);
  mlpmm_kernel<<<dim3(768), 512, 0, stream>>>(
      KEY, QUERY, W1b, W2b, W3b, Wo1b, Wo2b, Wo3b, sp, Ks, Qs, Wo);
  attn_kernel<<<dim3(NQQ / 32, B_DIM), 256, 0, stream>>>(Ks, Qs, Vtg, Wo, outf);
}